// Round 2
// baseline (2535.104 us; speedup 1.0000x reference)
//
#include <hip/hip_runtime.h>

typedef unsigned short ushort_t;
typedef unsigned int uint_t;

#define NNODE 2000
#define NB 8
#define LSEQ 12
#define HDIM 64
#define NEDGE 16000
#define NSEQ (NNODE * NB)            // 16000 sequences
#define OUT1_ELEMS (NNODE * NB * LSEQ * HDIM)   // 12,288,000
#define OUT1_BYTES (OUT1_ELEMS * 2)             // bf16 intermediate: 24,576,000
#define AGG_BYTES  (OUT1_ELEMS * 4)             // fp32: 49,152,000

__device__ __forceinline__ float bflo(uint_t u) { return __uint_as_float(u << 16); }
__device__ __forceinline__ float bfhi(uint_t u) { return __uint_as_float(u & 0xffff0000u); }
__device__ __forceinline__ float bf1(ushort_t u) { return __uint_as_float(((uint_t)u) << 16); }
__device__ __forceinline__ ushort_t fbf(float f) {
    uint_t x = __float_as_uint(f);
    uint_t r = x + 0x7fffu + ((x >> 16) & 1u);   // RNE
    return (ushort_t)(r >> 16);
}
__device__ __forceinline__ float sigm(float x) { return 1.f / (1.f + __expf(-x)); }
__device__ __forceinline__ float tanh_fast(float x) { return 2.f / (1.f + __expf(-2.f * x)) - 1.f; }

// ---------------------------------------------------------------------------
// GRU1: input fp32 [NSEQ, L, D=2] -> out1 bf16 [NSEQ, L, H] (own intermediate),
// h1 fp32 -> d_out. Wave per sequence, lane = h, Whh rows in 192 VGPRs/lane.
// ---------------------------------------------------------------------------
__global__ __launch_bounds__(256) void gru1_kernel(
    const float* __restrict__ data, const float* __restrict__ Wih,
    const float* __restrict__ Whh, const float* __restrict__ bih,
    const float* __restrict__ bhh, ushort_t* __restrict__ out1,
    float* __restrict__ h1out)
{
    const int lane = threadIdx.x & 63;
    const int wave = threadIdx.x >> 6;
    const int s = blockIdx.x * 4 + wave;
    if (s >= NSEQ) return;

    float wh[3][64];
#pragma unroll
    for (int g = 0; g < 3; ++g) {
        const float4* row = (const float4*)(Whh + (g * 64 + lane) * 64);
#pragma unroll
        for (int d = 0; d < 16; ++d) {
            float4 v = row[d];
            wh[g][4 * d + 0] = v.x; wh[g][4 * d + 1] = v.y;
            wh[g][4 * d + 2] = v.z; wh[g][4 * d + 3] = v.w;
        }
    }
    float wi0[3], wi1[3], bi[3], bh[3];
#pragma unroll
    for (int g = 0; g < 3; ++g) {
        float2 v = ((const float2*)Wih)[g * 64 + lane];   // row (g*64+h) of [192][2]
        wi0[g] = v.x; wi1[g] = v.y;
        bi[g] = bih[g * 64 + lane];
        bh[g] = bhh[g * 64 + lane];
    }

    const float2* xd = ((const float2*)data) + s * LSEQ;  // 2 fp32 per step
    ushort_t* ob = out1 + s * (LSEQ * HDIM);
    float h = 0.f;
    for (int t = 0; t < LSEQ; ++t) {
        float2 xu = xd[t];
        float g0 = bh[0], g1 = bh[1], g2 = bh[2];
#pragma unroll
        for (int k = 0; k < 64; ++k) {
            float hk = __shfl(h, k);
            g0 += wh[0][k] * hk;
            g1 += wh[1][k] * hk;
            g2 += wh[2][k] * hk;
        }
        float i0 = bi[0] + wi0[0] * xu.x + wi1[0] * xu.y;
        float i1 = bi[1] + wi0[1] * xu.x + wi1[1] * xu.y;
        float i2 = bi[2] + wi0[2] * xu.x + wi1[2] * xu.y;
        float r = sigm(i0 + g0);
        float z = sigm(i1 + g1);
        float n = tanh_fast(i2 + r * g2);
        h = (1.f - z) * n + z * h;
        ob[t * HDIM + lane] = fbf(h);
    }
    h1out[s * HDIM + lane] = h;
}

// ---------------------------------------------------------------------------
// MetaGAT: one block (256 thr) per edge. Per-edge MLP -> w[128][64] fp32 LDS,
// states_i/j staged bf16 in LDS, in-register softmax over B, atomic agg.
// ---------------------------------------------------------------------------
__global__ __launch_bounds__(256) void gat_kernel(
    const ushort_t* __restrict__ out1, const float* __restrict__ features,
    const int* __restrict__ edges,
    const float* __restrict__ W1, const float* __restrict__ b1,
    const float* __restrict__ W2, const float* __restrict__ b2,
    const float* __restrict__ W3, const float* __restrict__ b3,
    float* __restrict__ agg)
{
    __shared__ float w_s[128 * 64];                         // 32 KB
    __shared__ ushort_t si[96 * 64] __attribute__((aligned(16)));  // 12 KB
    __shared__ ushort_t sj[96 * 64] __attribute__((aligned(16)));  // 12 KB
    __shared__ float mlp1[16];
    __shared__ float a_s[2];

    const int tid = threadIdx.x;
    const int e = blockIdx.x;
    int i, j;
    if (e < NEDGE) { j = edges[e]; i = edges[NEDGE + e]; }  // src, dst
    else { i = j = e - NEDGE; }                             // self loop

    // stage states (12 KB per node, coalesced dword copies of bf16 pairs)
    {
        const uint_t* pi = (const uint_t*)(out1 + i * (NB * LSEQ * HDIM));
        const uint_t* pj = (const uint_t*)(out1 + j * (NB * LSEQ * HDIM));
        uint_t* di = (uint_t*)si;
        uint_t* dj = (uint_t*)sj;
        for (int idx = tid; idx < 3072; idx += 256) { di[idx] = pi[idx]; dj[idx] = pj[idx]; }
    }
    // edge MLP layer 1: feats = [features[i], features[j]]
    if (tid < 16) {
        float acc = b1[tid];
        const float* wr = W1 + tid * 128;
        for (int k = 0; k < 64; ++k) acc += features[i * 64 + k] * wr[k];
        for (int k = 0; k < 64; ++k) acc += features[j * 64 + k] * wr[64 + k];
        mlp1[tid] = sigm(acc);
    }
    __syncthreads();
    if (tid < 2) {
        float acc = b2[tid];
        for (int k = 0; k < 16; ++k) acc += mlp1[k] * W2[tid * 16 + k];
        a_s[tid] = sigm(acc);
    }
    __syncthreads();
    const float a0 = a_s[0], a1 = a_s[1];
    for (int m = tid; m < 8192; m += 256) {
        float2 wv = ((const float2*)W3)[m];         // W3[m][0], W3[m][1]
        w_s[m] = a0 * wv.x + a1 * wv.y + b3[m];
    }
    __syncthreads();

    const int lane = tid & 63;   // h
    const int wv = tid >> 6;
    const int l0 = wv * 3;       // wave covers l0..l0+2, all 8 b

    float acc[8][3];
#pragma unroll
    for (int b = 0; b < 8; ++b)
#pragma unroll
        for (int d = 0; d < 3; ++d) acc[b][d] = 0.f;

    for (int kc = 0; kc < 16; ++kc) {
        float wreg[8];
#pragma unroll
        for (int q = 0; q < 8; ++q) wreg[q] = w_s[(kc * 8 + q) * 64 + lane];
        const ushort_t* sb = (kc < 8) ? si : sj;
        const int kk = (kc & 7) * 8;
#pragma unroll
        for (int b = 0; b < 8; ++b) {
#pragma unroll
            for (int d = 0; d < 3; ++d) {
                const int bl = b * 12 + l0 + d;
                uint4 p = *((const uint4*)(sb + bl * 64 + kk));  // broadcast read
                float a = acc[b][d];
                a += bflo(p.x) * wreg[0]; a += bfhi(p.x) * wreg[1];
                a += bflo(p.y) * wreg[2]; a += bfhi(p.y) * wreg[3];
                a += bflo(p.z) * wreg[4]; a += bfhi(p.z) * wreg[5];
                a += bflo(p.w) * wreg[6]; a += bfhi(p.w) * wreg[7];
                acc[b][d] = a;
            }
        }
    }

#pragma unroll
    for (int d = 0; d < 3; ++d) {
        const int l = l0 + d;
        float v[8];
        float mx = -1e30f;
#pragma unroll
        for (int b = 0; b < 8; ++b) {
            float x = acc[b][d];
            x = x > 0.f ? x : 0.01f * x;   // leaky_relu(0.01)
            v[b] = x;
            mx = fmaxf(mx, x);
        }
        float sum = 0.f;
#pragma unroll
        for (int b = 0; b < 8; ++b) { v[b] = __expf(v[b] - mx); sum += v[b]; }
        float inv = 1.f / sum;
#pragma unroll
        for (int b = 0; b < 8; ++b) {
            const int bl = b * 12 + l;
            float msg = v[b] * inv * bf1(sj[bl * 64 + lane]);
            atomicAdd(&agg[(i * 96 + bl) * 64 + lane], msg);
        }
    }
}

// ---------------------------------------------------------------------------
// GRU2: input relu(agg) [NSEQ, L, H=64] fp32 -> h2 fp32. Two phases sharing
// the 192-VGPR weight array: (1) gi for all t into LDS, (2) recurrence.
// ---------------------------------------------------------------------------
__global__ __launch_bounds__(256) void gru2_kernel(
    const float* __restrict__ agg, const float* __restrict__ Wih,
    const float* __restrict__ Whh, const float* __restrict__ bih,
    const float* __restrict__ bhh, float* __restrict__ h2out)
{
    __shared__ float gi_lds[4][LSEQ][3][64];   // 36 KB
    const int lane = threadIdx.x & 63;
    const int wave = threadIdx.x >> 6;
    const int s = blockIdx.x * 4 + wave;
    if (s >= NSEQ) return;

    float bi[3], bh[3];
#pragma unroll
    for (int g = 0; g < 3; ++g) {
        bi[g] = bih[g * 64 + lane];
        bh[g] = bhh[g * 64 + lane];
    }

    float wr[3][64];
    // phase 1: Wih2, compute gi[t] for all steps (independent of recurrence)
#pragma unroll
    for (int g = 0; g < 3; ++g) {
        const float4* row = (const float4*)(Wih + (g * 64 + lane) * 64);
#pragma unroll
        for (int d = 0; d < 16; ++d) {
            float4 v = row[d];
            wr[g][4 * d + 0] = v.x; wr[g][4 * d + 1] = v.y;
            wr[g][4 * d + 2] = v.z; wr[g][4 * d + 3] = v.w;
        }
    }
    const float* xb = agg + s * (LSEQ * HDIM);
    for (int t = 0; t < LSEQ; ++t) {
        float xv = xb[t * HDIM + lane];
        xv = xv > 0.f ? xv : 0.f;           // relu(agg) == out2
        float g0 = bi[0], g1 = bi[1], g2 = bi[2];
#pragma unroll
        for (int k = 0; k < 64; ++k) {
            float xk = __shfl(xv, k);
            g0 += wr[0][k] * xk;
            g1 += wr[1][k] * xk;
            g2 += wr[2][k] * xk;
        }
        gi_lds[wave][t][0][lane] = g0;
        gi_lds[wave][t][1][lane] = g1;
        gi_lds[wave][t][2][lane] = g2;
    }
    // phase 2: Whh2, recurrence
#pragma unroll
    for (int g = 0; g < 3; ++g) {
        const float4* row = (const float4*)(Whh + (g * 64 + lane) * 64);
#pragma unroll
        for (int d = 0; d < 16; ++d) {
            float4 v = row[d];
            wr[g][4 * d + 0] = v.x; wr[g][4 * d + 1] = v.y;
            wr[g][4 * d + 2] = v.z; wr[g][4 * d + 3] = v.w;
        }
    }
    float h = 0.f;
    for (int t = 0; t < LSEQ; ++t) {
        float g0 = bh[0], g1 = bh[1], g2 = bh[2];
#pragma unroll
        for (int k = 0; k < 64; ++k) {
            float hk = __shfl(h, k);
            g0 += wr[0][k] * hk;
            g1 += wr[1][k] * hk;
            g2 += wr[2][k] * hk;
        }
        float i0 = gi_lds[wave][t][0][lane];
        float i1 = gi_lds[wave][t][1][lane];
        float i2 = gi_lds[wave][t][2][lane];
        float r = sigm(i0 + g0);
        float z = sigm(i1 + g1);
        float n = tanh_fast(i2 + r * g2);
        h = (1.f - z) * n + z * h;
    }
    h2out[s * HDIM + lane] = h;
}

extern "C" void kernel_launch(void* const* d_in, const int* in_sizes, int n_in,
                              void* d_out, int out_size, void* d_ws, size_t ws_size,
                              hipStream_t stream)
{
    const float* data     = (const float*)d_in[0];
    const float* features = (const float*)d_in[1];
    const int*   edges    = (const int*)d_in[2];
    const float* Wih1     = (const float*)d_in[3];
    const float* Whh1     = (const float*)d_in[4];
    const float* bih1     = (const float*)d_in[5];
    const float* bhh1     = (const float*)d_in[6];
    const float* W1       = (const float*)d_in[7];
    const float* b1       = (const float*)d_in[8];
    const float* W2       = (const float*)d_in[9];
    const float* b2       = (const float*)d_in[10];
    const float* W3       = (const float*)d_in[11];
    const float* b3       = (const float*)d_in[12];
    const float* Wih2     = (const float*)d_in[13];
    const float* Whh2     = (const float*)d_in[14];
    const float* bih2     = (const float*)d_in[15];
    const float* bhh2     = (const float*)d_in[16];

    float*    out  = (float*)d_out;
    char*     ws   = (char*)d_ws;
    ushort_t* out1 = (ushort_t*)ws;                    // bf16 intermediate
    float*    agg  = (float*)(ws + OUT1_BYTES);        // fp32 accumulator

    hipMemsetAsync(agg, 0, AGG_BYTES, stream);

    gru1_kernel<<<NSEQ / 4, 256, 0, stream>>>(data, Wih1, Whh1, bih1, bhh1, out1, out);
    gat_kernel<<<NEDGE + NNODE, 256, 0, stream>>>(out1, features, edges,
                                                  W1, b1, W2, b2, W3, b3, agg);
    gru2_kernel<<<NSEQ / 4, 256, 0, stream>>>(agg, Whh2 ? Wih2 : Wih2, Whh2, bih2, bhh2,
                                              out + NNODE * NB * HDIM);
}

// Round 3
// 1763.704 us; speedup vs baseline: 1.4374x; 1.4374x over previous
//
#include <hip/hip_runtime.h>

typedef unsigned short ushort_t;
typedef unsigned int uint_t;

#define NNODE 2000
#define NB 8
#define LSEQ 12
#define HDIM 64
#define NEDGE 16000
#define NSEQ (NNODE * NB)            // 16000 sequences
#define OUT1_ELEMS (NNODE * NB * LSEQ * HDIM)   // 12,288,000
#define OUT1_BYTES (OUT1_ELEMS * 2)             // bf16 intermediate: 24,576,000
#define AGG_BYTES  (OUT1_ELEMS * 4)             // fp32: 49,152,000

__device__ __forceinline__ float bflo(uint_t u) { return __uint_as_float(u << 16); }
__device__ __forceinline__ float bfhi(uint_t u) { return __uint_as_float(u & 0xffff0000u); }
__device__ __forceinline__ float bf1(ushort_t u) { return __uint_as_float(((uint_t)u) << 16); }
__device__ __forceinline__ ushort_t fbf(float f) {
    uint_t x = __float_as_uint(f);
    uint_t r = x + 0x7fffu + ((x >> 16) & 1u);   // RNE
    return (ushort_t)(r >> 16);
}
__device__ __forceinline__ float sigm(float x) { return 1.f / (1.f + __expf(-x)); }
__device__ __forceinline__ float tanh_fast(float x) { return 2.f / (1.f + __expf(-2.f * x)) - 1.f; }

// ---------------------------------------------------------------------------
// GRU1: lane = sequence (64 seq/block), 8 waves split the 64 h-outputs.
// Weights read uniformly -> s_load/SGPR operand FMAs. h exchanged via LDS.
// ---------------------------------------------------------------------------
__global__ __launch_bounds__(512) void gru1_kernel(
    const float* __restrict__ data, const float* __restrict__ Wih,
    const float* __restrict__ Whh, const float* __restrict__ bih,
    const float* __restrict__ bhh, ushort_t* __restrict__ out1,
    float* __restrict__ h1out)
{
    __shared__ float h_lds[64][65];
    const int tid = threadIdx.x;
    const int lane = tid & 63;                                   // sequence slot
    const int j0 = __builtin_amdgcn_readfirstlane((tid >> 6) * 8);  // h-col range
    const int s0 = blockIdx.x * 64;
    const int seq = s0 + lane;
    const int kk = tid & 63;
    const int sq = tid >> 6;

    // zero h_lds (h0 = 0)
#pragma unroll
    for (int p = 0; p < 8; ++p) h_lds[kk][sq + p * 8] = 0.f;

    float h[64];

    for (int t = 0; t < LSEQ; ++t) {
        __syncthreads();   // B1: h_lds ready (zeros at t=0, else prev write)
        // refresh full h vector for this lane's sequence (conflict-free: (k+lane)%32)
#pragma unroll
        for (int k = 0; k < 64; ++k) h[k] = h_lds[k][lane];
        const float2 xt = *(const float2*)(data + seq * (LSEQ * 2) + t * 2);

        float hn[8];
#pragma unroll
        for (int jj = 0; jj < 8; ++jj) {
            const int j = j0 + jj;
            float g[3], gi[3];
#pragma unroll
            for (int gg = 0; gg < 3; ++gg) {
                const int row = gg * 64 + j;                     // uniform
                const float* wr = Whh + row * 64;                // -> s_load
                float acc = bhh[row];
#pragma unroll
                for (int k = 0; k < 64; ++k) acc += wr[k] * h[k];
                g[gg] = acc;
                gi[gg] = bih[row] + Wih[row * 2] * xt.x + Wih[row * 2 + 1] * xt.y;
            }
            const float hold = h_lds[j][lane];                   // dynamic idx via LDS
            float r = sigm(gi[0] + g[0]);
            float z = sigm(gi[1] + g[1]);
            float n = tanh_fast(gi[2] + r * g[2]);
            hn[jj] = (1.f - z) * n + z * hold;
        }
        // out1 per-lane: 8 consecutive bf16 (16 B aligned)
        ushort_t ob[8];
#pragma unroll
        for (int jj = 0; jj < 8; ++jj) ob[jj] = fbf(hn[jj]);
        *(uint4*)(out1 + seq * (LSEQ * HDIM) + t * HDIM + j0) = *(uint4*)ob;

        __syncthreads();   // B2: all h_lds reads done
#pragma unroll
        for (int jj = 0; jj < 8; ++jj) h_lds[j0 + jj][lane] = hn[jj];
    }
    __syncthreads();       // B3
    // h1: coalesced from h_lds
#pragma unroll
    for (int p = 0; p < 8; ++p) {
        const int sqq = sq + p * 8;
        h1out[(s0 + sqq) * HDIM + kk] = h_lds[kk][sqq];
    }
}

// ---------------------------------------------------------------------------
// MetaGAT: one block (256 thr) per edge. Per-edge MLP -> w[128][64] fp32 LDS,
// states_i/j staged bf16 in LDS, in-register softmax over B, atomic agg.
// ---------------------------------------------------------------------------
__global__ __launch_bounds__(256) void gat_kernel(
    const ushort_t* __restrict__ out1, const float* __restrict__ features,
    const int* __restrict__ edges,
    const float* __restrict__ W1, const float* __restrict__ b1,
    const float* __restrict__ W2, const float* __restrict__ b2,
    const float* __restrict__ W3, const float* __restrict__ b3,
    float* __restrict__ agg)
{
    __shared__ float w_s[128 * 64];                         // 32 KB
    __shared__ ushort_t si[96 * 64] __attribute__((aligned(16)));  // 12 KB
    __shared__ ushort_t sj[96 * 64] __attribute__((aligned(16)));  // 12 KB
    __shared__ float mlp1[16];
    __shared__ float a_s[2];

    const int tid = threadIdx.x;
    const int e = blockIdx.x;
    int i, j;
    if (e < NEDGE) { j = edges[e]; i = edges[NEDGE + e]; }  // src, dst
    else { i = j = e - NEDGE; }                             // self loop

    // stage states (12 KB per node, coalesced dword copies of bf16 pairs)
    {
        const uint_t* pi = (const uint_t*)(out1 + i * (NB * LSEQ * HDIM));
        const uint_t* pj = (const uint_t*)(out1 + j * (NB * LSEQ * HDIM));
        uint_t* di = (uint_t*)si;
        uint_t* dj = (uint_t*)sj;
        for (int idx = tid; idx < 3072; idx += 256) { di[idx] = pi[idx]; dj[idx] = pj[idx]; }
    }
    // edge MLP layer 1: feats = [features[i], features[j]]
    if (tid < 16) {
        float acc = b1[tid];
        const float* wr = W1 + tid * 128;
        for (int k = 0; k < 64; ++k) acc += features[i * 64 + k] * wr[k];
        for (int k = 0; k < 64; ++k) acc += features[j * 64 + k] * wr[64 + k];
        mlp1[tid] = sigm(acc);
    }
    __syncthreads();
    if (tid < 2) {
        float acc = b2[tid];
        for (int k = 0; k < 16; ++k) acc += mlp1[k] * W2[tid * 16 + k];
        a_s[tid] = sigm(acc);
    }
    __syncthreads();
    const float a0 = a_s[0], a1 = a_s[1];
    for (int m = tid; m < 8192; m += 256) {
        float2 wv = ((const float2*)W3)[m];         // W3[m][0], W3[m][1]
        w_s[m] = a0 * wv.x + a1 * wv.y + b3[m];
    }
    __syncthreads();

    const int lane = tid & 63;   // h
    const int wv = tid >> 6;
    const int l0 = wv * 3;       // wave covers l0..l0+2, all 8 b

    float acc[8][3];
#pragma unroll
    for (int b = 0; b < 8; ++b)
#pragma unroll
        for (int d = 0; d < 3; ++d) acc[b][d] = 0.f;

    for (int kc = 0; kc < 16; ++kc) {
        float wreg[8];
#pragma unroll
        for (int q = 0; q < 8; ++q) wreg[q] = w_s[(kc * 8 + q) * 64 + lane];
        const ushort_t* sb = (kc < 8) ? si : sj;
        const int kk = (kc & 7) * 8;
#pragma unroll
        for (int b = 0; b < 8; ++b) {
#pragma unroll
            for (int d = 0; d < 3; ++d) {
                const int bl = b * 12 + l0 + d;
                uint4 p = *((const uint4*)(sb + bl * 64 + kk));  // broadcast read
                float a = acc[b][d];
                a += bflo(p.x) * wreg[0]; a += bfhi(p.x) * wreg[1];
                a += bflo(p.y) * wreg[2]; a += bfhi(p.y) * wreg[3];
                a += bflo(p.z) * wreg[4]; a += bfhi(p.z) * wreg[5];
                a += bflo(p.w) * wreg[6]; a += bfhi(p.w) * wreg[7];
                acc[b][d] = a;
            }
        }
    }

#pragma unroll
    for (int d = 0; d < 3; ++d) {
        const int l = l0 + d;
        float v[8];
        float mx = -1e30f;
#pragma unroll
        for (int b = 0; b < 8; ++b) {
            float x = acc[b][d];
            x = x > 0.f ? x : 0.01f * x;   // leaky_relu(0.01)
            v[b] = x;
            mx = fmaxf(mx, x);
        }
        float sum = 0.f;
#pragma unroll
        for (int b = 0; b < 8; ++b) { v[b] = __expf(v[b] - mx); sum += v[b]; }
        float inv = 1.f / sum;
#pragma unroll
        for (int b = 0; b < 8; ++b) {
            const int bl = b * 12 + l;
            float msg = v[b] * inv * bf1(sj[bl * 64 + lane]);
            atomicAdd(&agg[(i * 96 + bl) * 64 + lane], msg);
        }
    }
}

// ---------------------------------------------------------------------------
// GRU2: lane = sequence, same structure as GRU1 but x = relu(agg) is a full
// 64-vector per step, staged coalesced into LDS then held in 64 VGPRs.
// ---------------------------------------------------------------------------
__global__ __launch_bounds__(512) void gru2_kernel(
    const float* __restrict__ agg, const float* __restrict__ Wih,
    const float* __restrict__ Whh, const float* __restrict__ bih,
    const float* __restrict__ bhh, float* __restrict__ h2out)
{
    __shared__ float h_lds[64][65];
    __shared__ float x_lds[64][65];
    const int tid = threadIdx.x;
    const int lane = tid & 63;
    const int j0 = __builtin_amdgcn_readfirstlane((tid >> 6) * 8);
    const int s0 = blockIdx.x * 64;
    const int kk = tid & 63;
    const int sq = tid >> 6;

#pragma unroll
    for (int p = 0; p < 8; ++p) h_lds[kk][sq + p * 8] = 0.f;

    float h[64], x[64];

    for (int t = 0; t < LSEQ; ++t) {
        // stage x_t = relu(agg) for the block's 64 sequences (coalesced)
#pragma unroll
        for (int p = 0; p < 8; ++p) {
            const int sqq = sq + p * 8;
            float v = agg[(s0 + sqq) * (LSEQ * HDIM) + t * HDIM + kk];
            x_lds[kk][sqq] = v > 0.f ? v : 0.f;
        }
        __syncthreads();   // B1: x_lds + h_lds ready
#pragma unroll
        for (int k = 0; k < 64; ++k) h[k] = h_lds[k][lane];
#pragma unroll
        for (int k = 0; k < 64; ++k) x[k] = x_lds[k][lane];

        float hn[8];
#pragma unroll
        for (int jj = 0; jj < 8; ++jj) {
            const int j = j0 + jj;
            float g[3], gi[3];
#pragma unroll
            for (int gg = 0; gg < 3; ++gg) {
                const int row = gg * 64 + j;                     // uniform
                const float* wr = Whh + row * 64;                // -> s_load
                const float* wi = Wih + row * 64;                // -> s_load
                float acch = bhh[row];
                float acci = bih[row];
#pragma unroll
                for (int k = 0; k < 64; ++k) acch += wr[k] * h[k];
#pragma unroll
                for (int k = 0; k < 64; ++k) acci += wi[k] * x[k];
                g[gg] = acch;
                gi[gg] = acci;
            }
            const float hold = h_lds[j][lane];
            float r = sigm(gi[0] + g[0]);
            float z = sigm(gi[1] + g[1]);
            float n = tanh_fast(gi[2] + r * g[2]);
            hn[jj] = (1.f - z) * n + z * hold;
        }
        __syncthreads();   // B2: reads done
#pragma unroll
        for (int jj = 0; jj < 8; ++jj) h_lds[j0 + jj][lane] = hn[jj];
    }
    __syncthreads();       // B3
#pragma unroll
    for (int p = 0; p < 8; ++p) {
        const int sqq = sq + p * 8;
        h2out[(s0 + sqq) * HDIM + kk] = h_lds[kk][sqq];
    }
}

extern "C" void kernel_launch(void* const* d_in, const int* in_sizes, int n_in,
                              void* d_out, int out_size, void* d_ws, size_t ws_size,
                              hipStream_t stream)
{
    const float* data     = (const float*)d_in[0];
    const float* features = (const float*)d_in[1];
    const int*   edges    = (const int*)d_in[2];
    const float* Wih1     = (const float*)d_in[3];
    const float* Whh1     = (const float*)d_in[4];
    const float* bih1     = (const float*)d_in[5];
    const float* bhh1     = (const float*)d_in[6];
    const float* W1       = (const float*)d_in[7];
    const float* b1       = (const float*)d_in[8];
    const float* W2       = (const float*)d_in[9];
    const float* b2       = (const float*)d_in[10];
    const float* W3       = (const float*)d_in[11];
    const float* b3       = (const float*)d_in[12];
    const float* Wih2     = (const float*)d_in[13];
    const float* Whh2     = (const float*)d_in[14];
    const float* bih2     = (const float*)d_in[15];
    const float* bhh2     = (const float*)d_in[16];

    float*    out  = (float*)d_out;
    char*     ws   = (char*)d_ws;
    ushort_t* out1 = (ushort_t*)ws;                    // bf16 intermediate
    float*    agg  = (float*)(ws + OUT1_BYTES);        // fp32 accumulator

    hipMemsetAsync(agg, 0, AGG_BYTES, stream);

    gru1_kernel<<<NSEQ / 64, 512, 0, stream>>>(data, Wih1, Whh1, bih1, bhh1, out1, out);
    gat_kernel<<<NEDGE + NNODE, 256, 0, stream>>>(out1, features, edges,
                                                  W1, b1, W2, b2, W3, b3, agg);
    gru2_kernel<<<NSEQ / 64, 512, 0, stream>>>(agg, Wih2, Whh2, bih2, bhh2,
                                               out + NNODE * NB * HDIM);
}

// Round 4
// 1255.507 us; speedup vs baseline: 2.0192x; 1.4048x over previous
//
#include <hip/hip_runtime.h>

typedef unsigned short ushort_t;
typedef unsigned int uint_t;
typedef __attribute__((ext_vector_type(8))) short bf16x8;
typedef __attribute__((ext_vector_type(4))) float f32x4;

#define NNODE 2000
#define NB 8
#define LSEQ 12
#define HDIM 64
#define NEDGE 16000
#define NSEQ (NNODE * NB)            // 16000 sequences
#define OUT1_ELEMS (NNODE * NB * LSEQ * HDIM)   // 12,288,000
#define OUT1_BYTES (OUT1_ELEMS * 2)             // bf16 intermediate: 24,576,000
#define AGG_BYTES  (OUT1_ELEMS * 4)             // fp32: 49,152,000

__device__ __forceinline__ float bflo(uint_t u) { return __uint_as_float(u << 16); }
__device__ __forceinline__ float bfhi(uint_t u) { return __uint_as_float(u & 0xffff0000u); }
__device__ __forceinline__ float bf1(ushort_t u) { return __uint_as_float(((uint_t)u) << 16); }
__device__ __forceinline__ ushort_t fbf(float f) {
    uint_t x = __float_as_uint(f);
    uint_t r = x + 0x7fffu + ((x >> 16) & 1u);   // RNE
    return (ushort_t)(r >> 16);
}
__device__ __forceinline__ float sigm(float x) { return 1.f / (1.f + __expf(-x)); }
__device__ __forceinline__ float tanh_fast(float x) { return 2.f / (1.f + __expf(-2.f * x)) - 1.f; }

// ---------------------------------------------------------------------------
// GRU1: lane = sequence (64 seq/block), 8 waves split the 64 h-outputs.
// ---------------------------------------------------------------------------
__global__ __launch_bounds__(512) void gru1_kernel(
    const float* __restrict__ data, const float* __restrict__ Wih,
    const float* __restrict__ Whh, const float* __restrict__ bih,
    const float* __restrict__ bhh, ushort_t* __restrict__ out1,
    float* __restrict__ h1out)
{
    __shared__ float h_lds[64][65];
    const int tid = threadIdx.x;
    const int lane = tid & 63;                                   // sequence slot
    const int j0 = __builtin_amdgcn_readfirstlane((tid >> 6) * 8);  // h-col range
    const int s0 = blockIdx.x * 64;
    const int seq = s0 + lane;
    const int kk = tid & 63;
    const int sq = tid >> 6;

#pragma unroll
    for (int p = 0; p < 8; ++p) h_lds[kk][sq + p * 8] = 0.f;

    float h[64];

    for (int t = 0; t < LSEQ; ++t) {
        __syncthreads();   // B1: h_lds ready
#pragma unroll
        for (int k = 0; k < 64; ++k) h[k] = h_lds[k][lane];
        const float2 xt = *(const float2*)(data + seq * (LSEQ * 2) + t * 2);

        float hn[8];
#pragma unroll
        for (int jj = 0; jj < 8; ++jj) {
            const int j = j0 + jj;
            float g[3], gi[3];
#pragma unroll
            for (int gg = 0; gg < 3; ++gg) {
                const int row = gg * 64 + j;                     // uniform
                const float* wr = Whh + row * 64;                // -> s_load
                float acc = bhh[row];
#pragma unroll
                for (int k = 0; k < 64; ++k) acc += wr[k] * h[k];
                g[gg] = acc;
                gi[gg] = bih[row] + Wih[row * 2] * xt.x + Wih[row * 2 + 1] * xt.y;
            }
            const float hold = h_lds[j][lane];
            float r = sigm(gi[0] + g[0]);
            float z = sigm(gi[1] + g[1]);
            float n = tanh_fast(gi[2] + r * g[2]);
            hn[jj] = (1.f - z) * n + z * hold;
        }
        ushort_t ob[8];
#pragma unroll
        for (int jj = 0; jj < 8; ++jj) ob[jj] = fbf(hn[jj]);
        *(uint4*)(out1 + seq * (LSEQ * HDIM) + t * HDIM + j0) = *(uint4*)ob;

        __syncthreads();   // B2: reads done
#pragma unroll
        for (int jj = 0; jj < 8; ++jj) h_lds[j0 + jj][lane] = hn[jj];
    }
    __syncthreads();       // B3
#pragma unroll
    for (int p = 0; p < 8; ++p) {
        const int sqq = sq + p * 8;
        h1out[(s0 + sqq) * HDIM + kk] = h_lds[kk][sqq];
    }
}

// ---------------------------------------------------------------------------
// MetaGAT (MFMA): one block (256 thr) per edge.
// S[96][136] bf16 in LDS, rows permuted row = l*8+b; cols 0-63 = states_i,
// 64-127 = states_j. Einsum via mfma_f32_16x16x32_bf16: per wave one 16-col
// N-strip, 6 M-tiles x 4 K-steps. B-frags (per-edge w) built in registers
// from W3/b3. Softmax over b fully in-register (shfl_xor 16). fp32 atomics.
// ---------------------------------------------------------------------------
__global__ __launch_bounds__(256) void gat_kernel(
    const ushort_t* __restrict__ out1, const float* __restrict__ features,
    const int* __restrict__ edges,
    const float* __restrict__ W1, const float* __restrict__ b1,
    const float* __restrict__ W2, const float* __restrict__ b2,
    const float* __restrict__ W3, const float* __restrict__ b3,
    float* __restrict__ agg)
{
    __shared__ ushort_t S[96][136] __attribute__((aligned(16)));   // 26112 B
    __shared__ float mlp1[16];
    __shared__ float a_s[2];

    const int tid = threadIdx.x;
    const int e = blockIdx.x;
    int i, j;
    if (e < NEDGE) { j = edges[e]; i = edges[NEDGE + e]; }  // src, dst
    else { i = j = e - NEDGE; }                             // self loop

    // ---- stage S: 192 source rows (96 i, 96 j) x 8 uint4 chunks ----
    {
        const ushort_t* pi = out1 + i * (NB * LSEQ * HDIM);
        const ushort_t* pj = out1 + j * (NB * LSEQ * HDIM);
#pragma unroll
        for (int p = 0; p < 6; ++p) {
            const int idx = tid + p * 256;        // 0..1535
            const int rid = idx >> 3, c = idx & 7;
            const int isj = (rid >= 96);
            const int r = isj ? rid - 96 : rid;   // src row = b*12 + l
            const int b = r / 12, l = r - b * 12;
            const ushort_t* src = (isj ? pj : pi) + r * 64 + c * 8;
            uint4 v = *(const uint4*)src;
            *(uint4*)&S[l * 8 + b][c * 8 + (isj ? 64 : 0)] = v;
        }
    }

    // ---- edge MLP layer 1 on wave 0: o = lane>>2, q = lane&3 ----
    if (tid < 64) {
        const int o = tid >> 2, q = tid & 3;
        const float* fsrc = (q < 2) ? (features + i * 64 + q * 32)
                                    : (features + j * 64 + (q - 2) * 32);
        const float* wsrc = W1 + o * 128 + q * 32;
        float acc = 0.f;
#pragma unroll
        for (int k = 0; k < 32; ++k) acc += fsrc[k] * wsrc[k];
        acc += __shfl_xor(acc, 1);
        acc += __shfl_xor(acc, 2);
        if (q == 0) mlp1[o] = sigm(acc + b1[o]);
    }
    __syncthreads();
    // ---- layer 2: lanes 0..31, o2 = lane>>4, k = lane&15 ----
    if (tid < 32) {
        const int o2 = tid >> 4, k = tid & 15;
        float p = mlp1[k] * W2[o2 * 16 + k];
        p += __shfl_xor(p, 1);
        p += __shfl_xor(p, 2);
        p += __shfl_xor(p, 4);
        p += __shfl_xor(p, 8);
        if (k == 0) a_s[o2] = sigm(p + b2[o2]);
    }
    __syncthreads();

    const float a0 = a_s[0], a1 = a_s[1];
    const int wv = tid >> 6;          // N-strip
    const int r = tid & 15;           // within-tile col (N) / row (M for A)
    const int quad = (tid >> 4) & 3;  // k-quad / C-row group
    const int n = wv * 16 + r;        // global output column h

    // ---- B-fragments in registers: w[k][n] for k = ks*32 + quad*8 + jj ----
    bf16x8 bfrag[4];
#pragma unroll
    for (int ks = 0; ks < 4; ++ks) {
        bf16x8 f;
#pragma unroll
        for (int jj = 0; jj < 8; ++jj) {
            const int m = (ks * 32 + quad * 8 + jj) * 64 + n;
            float2 w2 = ((const float2*)W3)[m];
            float w = fmaf(a1, w2.y, fmaf(a0, w2.x, b3[m]));
            f[jj] = (short)fbf(w);
        }
        bfrag[ks] = f;
    }

    // ---- 6 M-tiles: MFMA einsum + in-register softmax + atomic agg ----
    for (int mt = 0; mt < 6; ++mt) {
        f32x4 acc = {0.f, 0.f, 0.f, 0.f};
#pragma unroll
        for (int ks = 0; ks < 4; ++ks) {
            bf16x8 afrag = *(const bf16x8*)&S[mt * 16 + r][ks * 32 + quad * 8];
            acc = __builtin_amdgcn_mfma_f32_16x16x32_bf16(afrag, bfrag[ks], acc, 0, 0, 0);
        }
        // leaky_relu + softmax over b (8 rows: quads {0,1} / {2,3}, xor 16)
        float v[4];
#pragma unroll
        for (int g2 = 0; g2 < 4; ++g2) {
            float x = acc[g2];
            v[g2] = x > 0.f ? x : 0.01f * x;
        }
        float mx = fmaxf(fmaxf(v[0], v[1]), fmaxf(v[2], v[3]));
        mx = fmaxf(mx, __shfl_xor(mx, 16));
        float s = 0.f;
#pragma unroll
        for (int g2 = 0; g2 < 4; ++g2) { v[g2] = __expf(v[g2] - mx); s += v[g2]; }
        s += __shfl_xor(s, 16);
        const float inv = 1.f / s;
#pragma unroll
        for (int g2 = 0; g2 < 4; ++g2) {
            const int row = mt * 16 + quad * 4 + g2;   // = l*8 + b
            const int b = row & 7, l = row >> 3;
            const float msg = v[g2] * inv * bf1(S[row][64 + n]);
            atomicAdd(&agg[(i * 96 + b * 12 + l) * 64 + n], msg);
        }
    }
}

// ---------------------------------------------------------------------------
// GRU2: lane = sequence, x = relu(agg) staged via LDS, held in 64 VGPRs.
// ---------------------------------------------------------------------------
__global__ __launch_bounds__(512) void gru2_kernel(
    const float* __restrict__ agg, const float* __restrict__ Wih,
    const float* __restrict__ Whh, const float* __restrict__ bih,
    const float* __restrict__ bhh, float* __restrict__ h2out)
{
    __shared__ float h_lds[64][65];
    __shared__ float x_lds[64][65];
    const int tid = threadIdx.x;
    const int lane = tid & 63;
    const int j0 = __builtin_amdgcn_readfirstlane((tid >> 6) * 8);
    const int s0 = blockIdx.x * 64;
    const int kk = tid & 63;
    const int sq = tid >> 6;

#pragma unroll
    for (int p = 0; p < 8; ++p) h_lds[kk][sq + p * 8] = 0.f;

    float h[64], x[64];

    for (int t = 0; t < LSEQ; ++t) {
#pragma unroll
        for (int p = 0; p < 8; ++p) {
            const int sqq = sq + p * 8;
            float v = agg[(s0 + sqq) * (LSEQ * HDIM) + t * HDIM + kk];
            x_lds[kk][sqq] = v > 0.f ? v : 0.f;
        }
        __syncthreads();   // B1
#pragma unroll
        for (int k = 0; k < 64; ++k) h[k] = h_lds[k][lane];
#pragma unroll
        for (int k = 0; k < 64; ++k) x[k] = x_lds[k][lane];

        float hn[8];
#pragma unroll
        for (int jj = 0; jj < 8; ++jj) {
            const int j = j0 + jj;
            float g[3], gi[3];
#pragma unroll
            for (int gg = 0; gg < 3; ++gg) {
                const int row = gg * 64 + j;                     // uniform
                const float* wr = Whh + row * 64;                // -> s_load
                const float* wi = Wih + row * 64;                // -> s_load
                float acch = bhh[row];
                float acci = bih[row];
#pragma unroll
                for (int k = 0; k < 64; ++k) acch += wr[k] * h[k];
#pragma unroll
                for (int k = 0; k < 64; ++k) acci += wi[k] * x[k];
                g[gg] = acch;
                gi[gg] = acci;
            }
            const float hold = h_lds[j][lane];
            float r = sigm(gi[0] + g[0]);
            float z = sigm(gi[1] + g[1]);
            float n = tanh_fast(gi[2] + r * g[2]);
            hn[jj] = (1.f - z) * n + z * hold;
        }
        __syncthreads();   // B2
#pragma unroll
        for (int jj = 0; jj < 8; ++jj) h_lds[j0 + jj][lane] = hn[jj];
    }
    __syncthreads();       // B3
#pragma unroll
    for (int p = 0; p < 8; ++p) {
        const int sqq = sq + p * 8;
        h2out[(s0 + sqq) * HDIM + kk] = h_lds[kk][sqq];
    }
}

extern "C" void kernel_launch(void* const* d_in, const int* in_sizes, int n_in,
                              void* d_out, int out_size, void* d_ws, size_t ws_size,
                              hipStream_t stream)
{
    const float* data     = (const float*)d_in[0];
    const float* features = (const float*)d_in[1];
    const int*   edges    = (const int*)d_in[2];
    const float* Wih1     = (const float*)d_in[3];
    const float* Whh1     = (const float*)d_in[4];
    const float* bih1     = (const float*)d_in[5];
    const float* bhh1     = (const float*)d_in[6];
    const float* W1       = (const float*)d_in[7];
    const float* b1       = (const float*)d_in[8];
    const float* W2       = (const float*)d_in[9];
    const float* b2       = (const float*)d_in[10];
    const float* W3       = (const float*)d_in[11];
    const float* b3       = (const float*)d_in[12];
    const float* Wih2     = (const float*)d_in[13];
    const float* Whh2     = (const float*)d_in[14];
    const float* bih2     = (const float*)d_in[15];
    const float* bhh2     = (const float*)d_in[16];

    float*    out  = (float*)d_out;
    char*     ws   = (char*)d_ws;
    ushort_t* out1 = (ushort_t*)ws;                    // bf16 intermediate
    float*    agg  = (float*)(ws + OUT1_BYTES);        // fp32 accumulator

    hipMemsetAsync(agg, 0, AGG_BYTES, stream);

    gru1_kernel<<<NSEQ / 64, 512, 0, stream>>>(data, Wih1, Whh1, bih1, bhh1, out1, out);
    gat_kernel<<<NEDGE + NNODE, 256, 0, stream>>>(out1, features, edges,
                                                  W1, b1, W2, b2, W3, b3, agg);
    gru2_kernel<<<NSEQ / 64, 512, 0, stream>>>(agg, Wih2, Whh2, bih2, bhh2,
                                               out + NNODE * NB * HDIM);
}

// Round 5
// 511.574 us; speedup vs baseline: 4.9555x; 2.4542x over previous
//
#include <hip/hip_runtime.h>

typedef unsigned short ushort_t;
typedef unsigned int uint_t;
typedef __attribute__((ext_vector_type(8))) short bf16x8;
typedef __attribute__((ext_vector_type(4))) float f32x4;

#define NNODE 2000
#define NB 8
#define LSEQ 12
#define HDIM 64
#define NEDGE 16000
#define NSEQ (NNODE * NB)            // 16000 sequences
#define OUT1_ELEMS (NNODE * NB * LSEQ * HDIM)   // 12,288,000
#define OUT1_BYTES (OUT1_ELEMS * 2)             // bf16 intermediate: 24,576,000
#define AGG_BYTES  (OUT1_ELEMS * 4)             // fp32: 49,152,000

__device__ __forceinline__ float bflo(uint_t u) { return __uint_as_float(u << 16); }
__device__ __forceinline__ float bfhi(uint_t u) { return __uint_as_float(u & 0xffff0000u); }
__device__ __forceinline__ float bf1(ushort_t u) { return __uint_as_float(((uint_t)u) << 16); }
__device__ __forceinline__ ushort_t fbf(float f) {
    uint_t x = __float_as_uint(f);
    uint_t r = x + 0x7fffu + ((x >> 16) & 1u);   // RNE
    return (ushort_t)(r >> 16);
}
__device__ __forceinline__ float sigm(float x) { return 1.f / (1.f + __expf(-x)); }
__device__ __forceinline__ float tanh_fast(float x) { return 2.f / (1.f + __expf(-2.f * x)) - 1.f; }

// ===========================================================================
// MFMA GRU geometry (both GRUs): block = 64 sequences, 512 thr = 8 waves as
// 2(M: seq halves) x 4(N: j-ranges of 16). Wave's 3 N-tiles = the 3 gates for
// its j-range (cols g*64+j), so r/z/n combine is lane-local in C-layout.
// B-frags (bf16 weights) pinned in VGPRs across all 12 steps.
// A-frag: A[m=lane&15][k=quad*8+jj]; B-frag: B[k=ks*32+quad*8+jj][n=lane&15];
// C: row(M)=quad*4+reg, col(N)=lane&15.  (layouts HW-verified in R3 gat)
// ===========================================================================

// ---------------------------------------------------------------------------
// GRU1: x_t is only 2-wide -> gi on VALU; gh via MFMA. out1 bf16 per step.
// ---------------------------------------------------------------------------
__global__ __launch_bounds__(512, 2) void gru1_kernel(
    const float* __restrict__ data, const float* __restrict__ Wih,
    const float* __restrict__ Whh, const float* __restrict__ bih,
    const float* __restrict__ bhh, ushort_t* __restrict__ out1,
    float* __restrict__ h1out)
{
    __shared__ ushort_t H[64][72] __attribute__((aligned(16)));  // 9216 B
    __shared__ float XD[64][26];                                 // 6656 B

    const int tid = threadIdx.x;
    const int wv = tid >> 6;
    const int mw = wv & 1, nw = wv >> 1;
    const int c = tid & 15;                 // N within tile = j offset
    const int quad = (tid >> 4) & 3;
    const int j = nw * 16 + c;
    const int s0 = blockIdx.x * 64;

    // zero H (cols 0..63)
    *(uint4*)&H[tid & 63][(tid >> 6) * 8] = uint4{0, 0, 0, 0};
    // stage all x: 64 seq x 24 floats
#pragma unroll
    for (int p = 0; p < 3; ++p) {
        const int flat = p * 512 + tid;     // 0..1535
        const int sl = flat / 24, q = flat - sl * 24;
        XD[sl][q] = data[(s0 + sl) * 24 + q];
    }

    // per-lane weights: Whh B-frags (3 gates x 2 ksteps), Wih/bias scalars
    bf16x8 Bh[3][2];
    float wi0[3], wi1[3], bi[3], bh[3];
#pragma unroll
    for (int g = 0; g < 3; ++g) {
        const int row = g * 64 + j;
        float2 wi = *(const float2*)(Wih + row * 2);
        wi0[g] = wi.x; wi1[g] = wi.y;
        bi[g] = bih[row]; bh[g] = bhh[row];
#pragma unroll
        for (int ks = 0; ks < 2; ++ks) {
            const float* wp = Whh + (row << 6) + ks * 32 + quad * 8;
            float4 wa = *(const float4*)wp;
            float4 wb = *(const float4*)(wp + 4);
            ushort_t tmp[8];
            tmp[0] = fbf(wa.x); tmp[1] = fbf(wa.y); tmp[2] = fbf(wa.z); tmp[3] = fbf(wa.w);
            tmp[4] = fbf(wb.x); tmp[5] = fbf(wb.y); tmp[6] = fbf(wb.z); tmp[7] = fbf(wb.w);
            Bh[g][ks] = *(bf16x8*)tmp;
        }
    }

    float hold[2][4];
#pragma unroll
    for (int mt = 0; mt < 2; ++mt)
#pragma unroll
        for (int rg = 0; rg < 4; ++rg) hold[mt][rg] = 0.f;

    for (int t = 0; t < LSEQ; ++t) {
        __syncthreads();   // A: H (+XD at t=0) visible
#pragma unroll
        for (int mt = 0; mt < 2; ++mt) {
            bf16x8 a0 = *(const bf16x8*)&H[mw * 32 + mt * 16 + c][quad * 8];
            bf16x8 a1 = *(const bf16x8*)&H[mw * 32 + mt * 16 + c][32 + quad * 8];
            f32x4 gh[3];
#pragma unroll
            for (int g = 0; g < 3; ++g) {
                f32x4 acc = {0.f, 0.f, 0.f, 0.f};
                acc = __builtin_amdgcn_mfma_f32_16x16x32_bf16(a0, Bh[g][0], acc, 0, 0, 0);
                acc = __builtin_amdgcn_mfma_f32_16x16x32_bf16(a1, Bh[g][1], acc, 0, 0, 0);
                gh[g] = acc;
            }
            ushort_t hnb[4];
#pragma unroll
            for (int rg = 0; rg < 4; ++rg) {
                const int sloc = mw * 32 + mt * 16 + quad * 4 + rg;
                float2 xp = *(const float2*)&XD[sloc][2 * t];
                float gr = bh[0] + gh[0][rg];
                float gz = bh[1] + gh[1][rg];
                float gn = bh[2] + gh[2][rg];
                float ir = bi[0] + wi0[0] * xp.x + wi1[0] * xp.y;
                float iz = bi[1] + wi0[1] * xp.x + wi1[1] * xp.y;
                float in = bi[2] + wi0[2] * xp.x + wi1[2] * xp.y;
                float r = sigm(ir + gr);
                float z = sigm(iz + gz);
                float n = tanh_fast(in + r * gn);
                float hv = (1.f - z) * n + z * hold[mt][rg];
                hold[mt][rg] = hv;
                hnb[rg] = fbf(hv);
            }
            __syncthreads();   // B (per mt half; both waves-halves in step)
#pragma unroll
            for (int rg = 0; rg < 4; ++rg) {
                const int sloc = mw * 32 + mt * 16 + quad * 4 + rg;
                H[sloc][j] = hnb[rg];
                out1[(s0 + sloc) * (LSEQ * HDIM) + t * HDIM + j] = hnb[rg];
            }
        }
    }
#pragma unroll
    for (int mt = 0; mt < 2; ++mt)
#pragma unroll
        for (int rg = 0; rg < 4; ++rg) {
            const int sloc = mw * 32 + mt * 16 + quad * 4 + rg;
            h1out[(s0 + sloc) * HDIM + j] = hold[mt][rg];
        }
}

// ---------------------------------------------------------------------------
// MetaGAT (MFMA): one block (256 thr) per edge.  (unchanged from R3)
// ---------------------------------------------------------------------------
__global__ __launch_bounds__(256) void gat_kernel(
    const ushort_t* __restrict__ out1, const float* __restrict__ features,
    const int* __restrict__ edges,
    const float* __restrict__ W1, const float* __restrict__ b1,
    const float* __restrict__ W2, const float* __restrict__ b2,
    const float* __restrict__ W3, const float* __restrict__ b3,
    float* __restrict__ agg)
{
    __shared__ ushort_t S[96][136] __attribute__((aligned(16)));   // 26112 B
    __shared__ float mlp1[16];
    __shared__ float a_s[2];

    const int tid = threadIdx.x;
    const int e = blockIdx.x;
    int i, j;
    if (e < NEDGE) { j = edges[e]; i = edges[NEDGE + e]; }  // src, dst
    else { i = j = e - NEDGE; }                             // self loop

    {
        const ushort_t* pi = out1 + i * (NB * LSEQ * HDIM);
        const ushort_t* pj = out1 + j * (NB * LSEQ * HDIM);
#pragma unroll
        for (int p = 0; p < 6; ++p) {
            const int idx = tid + p * 256;        // 0..1535
            const int rid = idx >> 3, c = idx & 7;
            const int isj = (rid >= 96);
            const int r = isj ? rid - 96 : rid;   // src row = b*12 + l
            const int b = r / 12, l = r - b * 12;
            const ushort_t* src = (isj ? pj : pi) + r * 64 + c * 8;
            uint4 v = *(const uint4*)src;
            *(uint4*)&S[l * 8 + b][c * 8 + (isj ? 64 : 0)] = v;
        }
    }

    if (tid < 64) {
        const int o = tid >> 2, q = tid & 3;
        const float* fsrc = (q < 2) ? (features + i * 64 + q * 32)
                                    : (features + j * 64 + (q - 2) * 32);
        const float* wsrc = W1 + o * 128 + q * 32;
        float acc = 0.f;
#pragma unroll
        for (int k = 0; k < 32; ++k) acc += fsrc[k] * wsrc[k];
        acc += __shfl_xor(acc, 1);
        acc += __shfl_xor(acc, 2);
        if (q == 0) mlp1[o] = sigm(acc + b1[o]);
    }
    __syncthreads();
    if (tid < 32) {
        const int o2 = tid >> 4, k = tid & 15;
        float p = mlp1[k] * W2[o2 * 16 + k];
        p += __shfl_xor(p, 1);
        p += __shfl_xor(p, 2);
        p += __shfl_xor(p, 4);
        p += __shfl_xor(p, 8);
        if (k == 0) a_s[o2] = sigm(p + b2[o2]);
    }
    __syncthreads();

    const float a0 = a_s[0], a1 = a_s[1];
    const int wv = tid >> 6;          // N-strip
    const int r = tid & 15;
    const int quad = (tid >> 4) & 3;
    const int n = wv * 16 + r;

    bf16x8 bfrag[4];
#pragma unroll
    for (int ks = 0; ks < 4; ++ks) {
        bf16x8 f;
#pragma unroll
        for (int jj = 0; jj < 8; ++jj) {
            const int m = (ks * 32 + quad * 8 + jj) * 64 + n;
            float2 w2 = ((const float2*)W3)[m];
            float w = fmaf(a1, w2.y, fmaf(a0, w2.x, b3[m]));
            f[jj] = (short)fbf(w);
        }
        bfrag[ks] = f;
    }

    for (int mt = 0; mt < 6; ++mt) {
        f32x4 acc = {0.f, 0.f, 0.f, 0.f};
#pragma unroll
        for (int ks = 0; ks < 4; ++ks) {
            bf16x8 afrag = *(const bf16x8*)&S[mt * 16 + r][ks * 32 + quad * 8];
            acc = __builtin_amdgcn_mfma_f32_16x16x32_bf16(afrag, bfrag[ks], acc, 0, 0, 0);
        }
        float v[4];
#pragma unroll
        for (int g2 = 0; g2 < 4; ++g2) {
            float x = acc[g2];
            v[g2] = x > 0.f ? x : 0.01f * x;
        }
        float mx = fmaxf(fmaxf(v[0], v[1]), fmaxf(v[2], v[3]));
        mx = fmaxf(mx, __shfl_xor(mx, 16));
        float s = 0.f;
#pragma unroll
        for (int g2 = 0; g2 < 4; ++g2) { v[g2] = __expf(v[g2] - mx); s += v[g2]; }
        s += __shfl_xor(s, 16);
        const float inv = 1.f / s;
#pragma unroll
        for (int g2 = 0; g2 < 4; ++g2) {
            const int row = mt * 16 + quad * 4 + g2;   // = l*8 + b
            const int b = row & 7, l = row >> 3;
            const float msg = v[g2] * inv * bf1(S[row][64 + n]);
            atomicAdd(&agg[(i * 96 + b * 12 + l) * 64 + n], msg);
        }
    }
}

// ---------------------------------------------------------------------------
// GRU2: gi AND gh via MFMA; x_t = relu(agg) staged bf16, next-step global
// load software-pipelined under the MFMAs.
// ---------------------------------------------------------------------------
__global__ __launch_bounds__(512, 2) void gru2_kernel(
    const float* __restrict__ agg, const float* __restrict__ Wih,
    const float* __restrict__ Whh, const float* __restrict__ bih,
    const float* __restrict__ bhh, float* __restrict__ h2out)
{
    __shared__ ushort_t H[64][72] __attribute__((aligned(16)));  // 9216 B
    __shared__ ushort_t X[64][72] __attribute__((aligned(16)));  // 9216 B

    const int tid = threadIdx.x;
    const int wv = tid >> 6;
    const int mw = wv & 1, nw = wv >> 1;
    const int c = tid & 15;
    const int quad = (tid >> 4) & 3;
    const int j = nw * 16 + c;
    const int s0 = blockIdx.x * 64;
    const int sl = tid >> 3, k0 = (tid & 7) * 8;   // X staging mapping

    *(uint4*)&H[tid & 63][(tid >> 6) * 8] = uint4{0, 0, 0, 0};

    // weights: Whh + Wih B-frags, biases
    bf16x8 Bh[3][2], Bi[3][2];
    float bi[3], bh[3];
#pragma unroll
    for (int g = 0; g < 3; ++g) {
        const int row = g * 64 + j;
        bi[g] = bih[row]; bh[g] = bhh[row];
#pragma unroll
        for (int ks = 0; ks < 2; ++ks) {
            const float* wp = Whh + (row << 6) + ks * 32 + quad * 8;
            float4 wa = *(const float4*)wp;
            float4 wb = *(const float4*)(wp + 4);
            ushort_t tmp[8];
            tmp[0] = fbf(wa.x); tmp[1] = fbf(wa.y); tmp[2] = fbf(wa.z); tmp[3] = fbf(wa.w);
            tmp[4] = fbf(wb.x); tmp[5] = fbf(wb.y); tmp[6] = fbf(wb.z); tmp[7] = fbf(wb.w);
            Bh[g][ks] = *(bf16x8*)tmp;
            const float* wp2 = Wih + (row << 6) + ks * 32 + quad * 8;
            float4 va = *(const float4*)wp2;
            float4 vb = *(const float4*)(wp2 + 4);
            tmp[0] = fbf(va.x); tmp[1] = fbf(va.y); tmp[2] = fbf(va.z); tmp[3] = fbf(va.w);
            tmp[4] = fbf(vb.x); tmp[5] = fbf(vb.y); tmp[6] = fbf(vb.z); tmp[7] = fbf(vb.w);
            Bi[g][ks] = *(bf16x8*)tmp;
        }
    }

    float hold[2][4];
#pragma unroll
    for (int mt = 0; mt < 2; ++mt)
#pragma unroll
        for (int rg = 0; rg < 4; ++rg) hold[mt][rg] = 0.f;

    // preload x_0
    float xr[8];
    {
        const float* gp = agg + (s0 + sl) * (LSEQ * HDIM) + k0;
        *(float4*)&xr[0] = *(const float4*)gp;
        *(float4*)&xr[4] = *(const float4*)(gp + 4);
    }

    for (int t = 0; t < LSEQ; ++t) {
        // write x_t (relu + bf16) into LDS
        {
            ushort_t xs[8];
#pragma unroll
            for (int q = 0; q < 8; ++q) xs[q] = fbf(xr[q] > 0.f ? xr[q] : 0.f);
            *(uint4*)&X[sl][k0] = *(uint4*)xs;
        }
        __syncthreads();   // A: X_t + H_t visible
        // issue next-step global load early (hidden under MFMAs)
        if (t < LSEQ - 1) {
            const float* gp = agg + (s0 + sl) * (LSEQ * HDIM) + (t + 1) * HDIM + k0;
            *(float4*)&xr[0] = *(const float4*)gp;
            *(float4*)&xr[4] = *(const float4*)(gp + 4);
        }
#pragma unroll
        for (int mt = 0; mt < 2; ++mt) {
            const int mrow = mw * 32 + mt * 16 + c;
            bf16x8 ah0 = *(const bf16x8*)&H[mrow][quad * 8];
            bf16x8 ah1 = *(const bf16x8*)&H[mrow][32 + quad * 8];
            bf16x8 ax0 = *(const bf16x8*)&X[mrow][quad * 8];
            bf16x8 ax1 = *(const bf16x8*)&X[mrow][32 + quad * 8];
            f32x4 gh[3], gi[3];
#pragma unroll
            for (int g = 0; g < 3; ++g) {
                f32x4 acc = {0.f, 0.f, 0.f, 0.f};
                acc = __builtin_amdgcn_mfma_f32_16x16x32_bf16(ah0, Bh[g][0], acc, 0, 0, 0);
                acc = __builtin_amdgcn_mfma_f32_16x16x32_bf16(ah1, Bh[g][1], acc, 0, 0, 0);
                gh[g] = acc;
                f32x4 acc2 = {0.f, 0.f, 0.f, 0.f};
                acc2 = __builtin_amdgcn_mfma_f32_16x16x32_bf16(ax0, Bi[g][0], acc2, 0, 0, 0);
                acc2 = __builtin_amdgcn_mfma_f32_16x16x32_bf16(ax1, Bi[g][1], acc2, 0, 0, 0);
                gi[g] = acc2;
            }
            ushort_t hnb[4];
#pragma unroll
            for (int rg = 0; rg < 4; ++rg) {
                float r = sigm(bi[0] + gi[0][rg] + bh[0] + gh[0][rg]);
                float z = sigm(bi[1] + gi[1][rg] + bh[1] + gh[1][rg]);
                float n = tanh_fast(bi[2] + gi[2][rg] + r * (bh[2] + gh[2][rg]));
                float hv = (1.f - z) * n + z * hold[mt][rg];
                hold[mt][rg] = hv;
                hnb[rg] = fbf(hv);
            }
            __syncthreads();   // B: all reads of H/X done
#pragma unroll
            for (int rg = 0; rg < 4; ++rg) {
                const int sloc = mw * 32 + mt * 16 + quad * 4 + rg;
                H[sloc][j] = hnb[rg];
            }
        }
    }
#pragma unroll
    for (int mt = 0; mt < 2; ++mt)
#pragma unroll
        for (int rg = 0; rg < 4; ++rg) {
            const int sloc = mw * 32 + mt * 16 + quad * 4 + rg;
            h2out[(s0 + sloc) * HDIM + j] = hold[mt][rg];
        }
}

extern "C" void kernel_launch(void* const* d_in, const int* in_sizes, int n_in,
                              void* d_out, int out_size, void* d_ws, size_t ws_size,
                              hipStream_t stream)
{
    const float* data     = (const float*)d_in[0];
    const float* features = (const float*)d_in[1];
    const int*   edges    = (const int*)d_in[2];
    const float* Wih1     = (const float*)d_in[3];
    const float* Whh1     = (const float*)d_in[4];
    const float* bih1     = (const float*)d_in[5];
    const float* bhh1     = (const float*)d_in[6];
    const float* W1       = (const float*)d_in[7];
    const float* b1       = (const float*)d_in[8];
    const float* W2       = (const float*)d_in[9];
    const float* b2       = (const float*)d_in[10];
    const float* W3       = (const float*)d_in[11];
    const float* b3       = (const float*)d_in[12];
    const float* Wih2     = (const float*)d_in[13];
    const float* Whh2     = (const float*)d_in[14];
    const float* bih2     = (const float*)d_in[15];
    const float* bhh2     = (const float*)d_in[16];

    float*    out  = (float*)d_out;
    char*     ws   = (char*)d_ws;
    ushort_t* out1 = (ushort_t*)ws;                    // bf16 intermediate
    float*    agg  = (float*)(ws + OUT1_BYTES);        // fp32 accumulator

    hipMemsetAsync(agg, 0, AGG_BYTES, stream);

    gru1_kernel<<<NSEQ / 64, 512, 0, stream>>>(data, Wih1, Whh1, bih1, bhh1, out1, out);
    gat_kernel<<<NEDGE + NNODE, 256, 0, stream>>>(out1, features, edges,
                                                  W1, b1, W2, b2, W3, b3, agg);
    gru2_kernel<<<NSEQ / 64, 512, 0, stream>>>(agg, Wih2, Whh2, bih2, bhh2,
                                               out + NNODE * NB * HDIM);
}

// Round 6
// 378.758 us; speedup vs baseline: 6.6932x; 1.3507x over previous
//
#include <hip/hip_runtime.h>

typedef unsigned short ushort_t;
typedef unsigned int uint_t;
typedef __attribute__((ext_vector_type(8))) short bf16x8;
typedef __attribute__((ext_vector_type(4))) float f32x4;

#define NNODE 2000
#define NB 8
#define LSEQ 12
#define HDIM 64
#define NEDGE 16000
#define NSEQ (NNODE * NB)            // 16000 sequences
#define OUT1_ELEMS (NNODE * NB * LSEQ * HDIM)   // 12,288,000
#define OUT1_BYTES (OUT1_ELEMS * 2)             // bf16 intermediate: 24,576,000
#define AGG_BYTES  (OUT1_ELEMS * 4)             // fp32: 49,152,000

__device__ __forceinline__ float bf1(ushort_t u) { return __uint_as_float(((uint_t)u) << 16); }
__device__ __forceinline__ ushort_t fbf(float f) {
    uint_t x = __float_as_uint(f);
    uint_t r = x + 0x7fffu + ((x >> 16) & 1u);   // RNE
    return (ushort_t)(r >> 16);
}
__device__ __forceinline__ float sigm(float x) { return 1.f / (1.f + __expf(-x)); }
__device__ __forceinline__ float tanh_fast(float x) { return 2.f / (1.f + __expf(-2.f * x)) - 1.f; }

// ===========================================================================
// MFMA GRU geometry: block = 64 sequences, 512 thr = 8 waves as 2(M) x 4(N).
// A-frag: A[m=lane&15][k=quad*8+jj]; B-frag: B[k=ks*32+quad*8+jj][n=lane&15];
// C: row(M)=quad*4+reg, col(N)=lane&15.  (layouts HW-verified in R3 gat)
// ===========================================================================

// ---------------------------------------------------------------------------
// GRU1: x_t is only 2-wide -> gi on VALU; gh via MFMA. out1 bf16 per step.
// ---------------------------------------------------------------------------
__global__ __launch_bounds__(512, 2) void gru1_kernel(
    const float* __restrict__ data, const float* __restrict__ Wih,
    const float* __restrict__ Whh, const float* __restrict__ bih,
    const float* __restrict__ bhh, ushort_t* __restrict__ out1,
    float* __restrict__ h1out)
{
    __shared__ ushort_t H[64][72] __attribute__((aligned(16)));  // 9216 B
    __shared__ float XD[64][26];                                 // 6656 B

    const int tid = threadIdx.x;
    const int wv = tid >> 6;
    const int mw = wv & 1, nw = wv >> 1;
    const int c = tid & 15;
    const int quad = (tid >> 4) & 3;
    const int j = nw * 16 + c;
    const int s0 = blockIdx.x * 64;

    *(uint4*)&H[tid & 63][(tid >> 6) * 8] = uint4{0, 0, 0, 0};
#pragma unroll
    for (int p = 0; p < 3; ++p) {
        const int flat = p * 512 + tid;     // 0..1535
        const int sl = flat / 24, q = flat - sl * 24;
        XD[sl][q] = data[(s0 + sl) * 24 + q];
    }

    bf16x8 Bh[3][2];
    float wi0[3], wi1[3], bi[3], bh[3];
#pragma unroll
    for (int g = 0; g < 3; ++g) {
        const int row = g * 64 + j;
        float2 wi = *(const float2*)(Wih + row * 2);
        wi0[g] = wi.x; wi1[g] = wi.y;
        bi[g] = bih[row]; bh[g] = bhh[row];
#pragma unroll
        for (int ks = 0; ks < 2; ++ks) {
            const float* wp = Whh + (row << 6) + ks * 32 + quad * 8;
            float4 wa = *(const float4*)wp;
            float4 wb = *(const float4*)(wp + 4);
            ushort_t tmp[8];
            tmp[0] = fbf(wa.x); tmp[1] = fbf(wa.y); tmp[2] = fbf(wa.z); tmp[3] = fbf(wa.w);
            tmp[4] = fbf(wb.x); tmp[5] = fbf(wb.y); tmp[6] = fbf(wb.z); tmp[7] = fbf(wb.w);
            Bh[g][ks] = *(bf16x8*)tmp;
        }
    }

    float hold[2][4];
#pragma unroll
    for (int mt = 0; mt < 2; ++mt)
#pragma unroll
        for (int rg = 0; rg < 4; ++rg) hold[mt][rg] = 0.f;

    for (int t = 0; t < LSEQ; ++t) {
        __syncthreads();   // A: H (+XD at t=0) visible
#pragma unroll
        for (int mt = 0; mt < 2; ++mt) {
            bf16x8 a0 = *(const bf16x8*)&H[mw * 32 + mt * 16 + c][quad * 8];
            bf16x8 a1 = *(const bf16x8*)&H[mw * 32 + mt * 16 + c][32 + quad * 8];
            f32x4 gh[3];
#pragma unroll
            for (int g = 0; g < 3; ++g) {
                f32x4 acc = {0.f, 0.f, 0.f, 0.f};
                acc = __builtin_amdgcn_mfma_f32_16x16x32_bf16(a0, Bh[g][0], acc, 0, 0, 0);
                acc = __builtin_amdgcn_mfma_f32_16x16x32_bf16(a1, Bh[g][1], acc, 0, 0, 0);
                gh[g] = acc;
            }
            ushort_t hnb[4];
#pragma unroll
            for (int rg = 0; rg < 4; ++rg) {
                const int sloc = mw * 32 + mt * 16 + quad * 4 + rg;
                float2 xp = *(const float2*)&XD[sloc][2 * t];
                float gr = bh[0] + gh[0][rg];
                float gz = bh[1] + gh[1][rg];
                float gn = bh[2] + gh[2][rg];
                float ir = bi[0] + wi0[0] * xp.x + wi1[0] * xp.y;
                float iz = bi[1] + wi0[1] * xp.x + wi1[1] * xp.y;
                float in = bi[2] + wi0[2] * xp.x + wi1[2] * xp.y;
                float r = sigm(ir + gr);
                float z = sigm(iz + gz);
                float n = tanh_fast(in + r * gn);
                float hv = (1.f - z) * n + z * hold[mt][rg];
                hold[mt][rg] = hv;
                hnb[rg] = fbf(hv);
            }
            __syncthreads();   // B
#pragma unroll
            for (int rg = 0; rg < 4; ++rg) {
                const int sloc = mw * 32 + mt * 16 + quad * 4 + rg;
                H[sloc][j] = hnb[rg];
                out1[(s0 + sloc) * (LSEQ * HDIM) + t * HDIM + j] = hnb[rg];
            }
        }
    }
#pragma unroll
    for (int mt = 0; mt < 2; ++mt)
#pragma unroll
        for (int rg = 0; rg < 4; ++rg) {
            const int sloc = mw * 32 + mt * 16 + quad * 4 + rg;
            h1out[(s0 + sloc) * HDIM + j] = hold[mt][rg];
        }
}

// ---------------------------------------------------------------------------
// CSR helpers: degree histogram -> single-block scan -> scatter src ids.
// ---------------------------------------------------------------------------
__global__ __launch_bounds__(256) void count_kernel(const int* __restrict__ edges,
                                                    int* __restrict__ degree)
{
    const int e = blockIdx.x * 256 + threadIdx.x;
    if (e < NEDGE) atomicAdd(&degree[edges[NEDGE + e]], 1);
}

__global__ __launch_bounds__(256) void scan_kernel(const int* __restrict__ degree,
                                                   int* __restrict__ rowstart)
{
    __shared__ int part[256];
    const int t = threadIdx.x;
    const int base = t * 8;
    int s = 0;
#pragma unroll
    for (int q = 0; q < 8; ++q) { const int idx = base + q; if (idx < NNODE) s += degree[idx]; }
    part[t] = s;
    __syncthreads();
    if (t == 0) {
        int run = 0;
        for (int u = 0; u < 256; ++u) { const int v = part[u]; part[u] = run; run += v; }
    }
    __syncthreads();
    int run = part[t];
#pragma unroll
    for (int q = 0; q < 8; ++q) {
        const int idx = base + q;
        if (idx < NNODE) { rowstart[idx] = run; run += degree[idx]; }
    }
}

__global__ __launch_bounds__(256) void scatter_kernel(const int* __restrict__ edges,
                                                      const int* __restrict__ rowstart,
                                                      int* __restrict__ cursor,
                                                      int* __restrict__ srcids)
{
    const int e = blockIdx.x * 256 + threadIdx.x;
    if (e < NEDGE) {
        const int d = edges[NEDGE + e];
        const int pos = atomicAdd(&cursor[d], 1);
        srcids[rowstart[d] + pos] = edges[e];   // store src node directly
    }
}

// ---------------------------------------------------------------------------
// MetaGAT (CSR, MFMA): one block (256 thr) per DST node. states_i pinned in
// LDS; per incoming edge (+self loop) restage states_j, per-edge MLP, MFMA
// einsum, in-register softmax, accumulate messages in 24 VGPRs/lane. One
// coalesced store at the end — NO atomics. W3/b3 pinned in 96 VGPRs/lane.
// ---------------------------------------------------------------------------
__global__ __launch_bounds__(256) void gat_csr_kernel(
    const ushort_t* __restrict__ out1, const float* __restrict__ features,
    const int* __restrict__ degree, const int* __restrict__ rowstart,
    const int* __restrict__ srcids,
    const float* __restrict__ W1, const float* __restrict__ b1,
    const float* __restrict__ W2, const float* __restrict__ b2,
    const float* __restrict__ W3, const float* __restrict__ b3,
    float* __restrict__ agg)
{
    __shared__ ushort_t S[96][136] __attribute__((aligned(16)));   // 26112 B
    __shared__ float mlp1[16];
    __shared__ float a_s[2];

    const int tid = threadIdx.x;
    const int i = blockIdx.x;
    const int deg = degree[i];
    const int rs = rowstart[i];

    const int wv = tid >> 6;          // N-strip
    const int r = tid & 15;
    const int quad = (tid >> 4) & 3;
    const int n = wv * 16 + r;

    // ---- stage states_i once (cols 0..63), row = l*8+b ----
    {
        const ushort_t* pi = out1 + i * (NB * LSEQ * HDIM);
#pragma unroll
        for (int p = 0; p < 3; ++p) {
            const int idx = tid + p * 256;        // 0..767
            const int rid = idx >> 3, c = idx & 7;
            const int b = rid / 12, l = rid - b * 12;
            *(uint4*)&S[l * 8 + b][c * 8] = *(const uint4*)(pi + rid * 64 + c * 8);
        }
    }

    // ---- pin this lane's W3 columns + b3 in registers (reused every edge) ----
    float w3a[32], w3b[32], w3c[32];
#pragma unroll
    for (int ks = 0; ks < 4; ++ks)
#pragma unroll
        for (int jj = 0; jj < 8; ++jj) {
            const int m = (ks * 32 + quad * 8 + jj) * 64 + n;
            float2 w2 = ((const float2*)W3)[m];
            w3a[ks * 8 + jj] = w2.x; w3b[ks * 8 + jj] = w2.y; w3c[ks * 8 + jj] = b3[m];
        }

    float accN[6][4];
#pragma unroll
    for (int mt = 0; mt < 6; ++mt)
#pragma unroll
        for (int g2 = 0; g2 < 4; ++g2) accN[mt][g2] = 0.f;

    for (int eo = 0; eo <= deg; ++eo) {
        const int j = (eo == 0) ? i : srcids[rs + eo - 1];
        __syncthreads();   // prior iteration's reads of S j-half done
        // stage states_j (cols 64..127)
        {
            const ushort_t* pj = out1 + j * (NB * LSEQ * HDIM);
#pragma unroll
            for (int p = 0; p < 3; ++p) {
                const int idx = tid + p * 256;
                const int rid = idx >> 3, c = idx & 7;
                const int b = rid / 12, l = rid - b * 12;
                *(uint4*)&S[l * 8 + b][64 + c * 8] = *(const uint4*)(pj + rid * 64 + c * 8);
            }
        }
        // edge MLP layer 1 on wave 0
        if (tid < 64) {
            const int o = tid >> 2, q = tid & 3;
            const float* fsrc = (q < 2) ? (features + i * 64 + q * 32)
                                        : (features + j * 64 + (q - 2) * 32);
            const float* wsrc = W1 + o * 128 + q * 32;
            float acc = 0.f;
#pragma unroll
            for (int k = 0; k < 32; ++k) acc += fsrc[k] * wsrc[k];
            acc += __shfl_xor(acc, 1);
            acc += __shfl_xor(acc, 2);
            if (q == 0) mlp1[o] = sigm(acc + b1[o]);
        }
        __syncthreads();
        if (tid < 32) {
            const int o2 = tid >> 4, k = tid & 15;
            float p = mlp1[k] * W2[o2 * 16 + k];
            p += __shfl_xor(p, 1);
            p += __shfl_xor(p, 2);
            p += __shfl_xor(p, 4);
            p += __shfl_xor(p, 8);
            if (k == 0) a_s[o2] = sigm(p + b2[o2]);
        }
        __syncthreads();
        const float a0 = a_s[0], a1 = a_s[1];

        // B-fragments from pinned registers (no memory)
        bf16x8 bfrag[4];
#pragma unroll
        for (int ks = 0; ks < 4; ++ks) {
            ushort_t tmp[8];
#pragma unroll
            for (int jj = 0; jj < 8; ++jj) {
                const int q = ks * 8 + jj;
                tmp[jj] = fbf(fmaf(a1, w3b[q], fmaf(a0, w3a[q], w3c[q])));
            }
            bfrag[ks] = *(bf16x8*)tmp;
        }

#pragma unroll
        for (int mt = 0; mt < 6; ++mt) {
            f32x4 acc = {0.f, 0.f, 0.f, 0.f};
#pragma unroll
            for (int ks = 0; ks < 4; ++ks) {
                bf16x8 afrag = *(const bf16x8*)&S[mt * 16 + r][ks * 32 + quad * 8];
                acc = __builtin_amdgcn_mfma_f32_16x16x32_bf16(afrag, bfrag[ks], acc, 0, 0, 0);
            }
            float v[4];
#pragma unroll
            for (int g2 = 0; g2 < 4; ++g2) {
                float x = acc[g2];
                v[g2] = x > 0.f ? x : 0.01f * x;
            }
            float mx = fmaxf(fmaxf(v[0], v[1]), fmaxf(v[2], v[3]));
            mx = fmaxf(mx, __shfl_xor(mx, 16));
            float s = 0.f;
#pragma unroll
            for (int g2 = 0; g2 < 4; ++g2) { v[g2] = __expf(v[g2] - mx); s += v[g2]; }
            s += __shfl_xor(s, 16);
            const float inv = 1.f / s;
#pragma unroll
            for (int g2 = 0; g2 < 4; ++g2) {
                const int row = mt * 16 + quad * 4 + g2;   // = l*8 + b
                accN[mt][g2] += v[g2] * inv * bf1(S[row][64 + n]);
            }
        }
    }

    // single non-atomic write of this node's aggregate
#pragma unroll
    for (int mt = 0; mt < 6; ++mt)
#pragma unroll
        for (int g2 = 0; g2 < 4; ++g2) {
            const int row = mt * 16 + quad * 4 + g2;   // = l*8 + b
            const int b = row & 7, l = row >> 3;
            agg[(i * 96 + b * 12 + l) * 64 + n] = accN[mt][g2];
        }
}

// ---------------------------------------------------------------------------
// GRU2: gi AND gh via MFMA; x_t = relu(agg) staged bf16, next-step global
// load software-pipelined under the MFMAs.
// ---------------------------------------------------------------------------
__global__ __launch_bounds__(512, 2) void gru2_kernel(
    const float* __restrict__ agg, const float* __restrict__ Wih,
    const float* __restrict__ Whh, const float* __restrict__ bih,
    const float* __restrict__ bhh, float* __restrict__ h2out)
{
    __shared__ ushort_t H[64][72] __attribute__((aligned(16)));  // 9216 B
    __shared__ ushort_t X[64][72] __attribute__((aligned(16)));  // 9216 B

    const int tid = threadIdx.x;
    const int wv = tid >> 6;
    const int mw = wv & 1, nw = wv >> 1;
    const int c = tid & 15;
    const int quad = (tid >> 4) & 3;
    const int j = nw * 16 + c;
    const int s0 = blockIdx.x * 64;
    const int sl = tid >> 3, k0 = (tid & 7) * 8;

    *(uint4*)&H[tid & 63][(tid >> 6) * 8] = uint4{0, 0, 0, 0};

    bf16x8 Bh[3][2], Bi[3][2];
    float bi[3], bh[3];
#pragma unroll
    for (int g = 0; g < 3; ++g) {
        const int row = g * 64 + j;
        bi[g] = bih[row]; bh[g] = bhh[row];
#pragma unroll
        for (int ks = 0; ks < 2; ++ks) {
            const float* wp = Whh + (row << 6) + ks * 32 + quad * 8;
            float4 wa = *(const float4*)wp;
            float4 wb = *(const float4*)(wp + 4);
            ushort_t tmp[8];
            tmp[0] = fbf(wa.x); tmp[1] = fbf(wa.y); tmp[2] = fbf(wa.z); tmp[3] = fbf(wa.w);
            tmp[4] = fbf(wb.x); tmp[5] = fbf(wb.y); tmp[6] = fbf(wb.z); tmp[7] = fbf(wb.w);
            Bh[g][ks] = *(bf16x8*)tmp;
            const float* wp2 = Wih + (row << 6) + ks * 32 + quad * 8;
            float4 va = *(const float4*)wp2;
            float4 vb = *(const float4*)(wp2 + 4);
            tmp[0] = fbf(va.x); tmp[1] = fbf(va.y); tmp[2] = fbf(va.z); tmp[3] = fbf(va.w);
            tmp[4] = fbf(vb.x); tmp[5] = fbf(vb.y); tmp[6] = fbf(vb.z); tmp[7] = fbf(vb.w);
            Bi[g][ks] = *(bf16x8*)tmp;
        }
    }

    float hold[2][4];
#pragma unroll
    for (int mt = 0; mt < 2; ++mt)
#pragma unroll
        for (int rg = 0; rg < 4; ++rg) hold[mt][rg] = 0.f;

    float xr[8];
    {
        const float* gp = agg + (s0 + sl) * (LSEQ * HDIM) + k0;
        *(float4*)&xr[0] = *(const float4*)gp;
        *(float4*)&xr[4] = *(const float4*)(gp + 4);
    }

    for (int t = 0; t < LSEQ; ++t) {
        {
            ushort_t xs[8];
#pragma unroll
            for (int q = 0; q < 8; ++q) xs[q] = fbf(xr[q] > 0.f ? xr[q] : 0.f);
            *(uint4*)&X[sl][k0] = *(uint4*)xs;
        }
        __syncthreads();   // A: X_t + H_t visible
        if (t < LSEQ - 1) {
            const float* gp = agg + (s0 + sl) * (LSEQ * HDIM) + (t + 1) * HDIM + k0;
            *(float4*)&xr[0] = *(const float4*)gp;
            *(float4*)&xr[4] = *(const float4*)(gp + 4);
        }
#pragma unroll
        for (int mt = 0; mt < 2; ++mt) {
            const int mrow = mw * 32 + mt * 16 + c;
            bf16x8 ah0 = *(const bf16x8*)&H[mrow][quad * 8];
            bf16x8 ah1 = *(const bf16x8*)&H[mrow][32 + quad * 8];
            bf16x8 ax0 = *(const bf16x8*)&X[mrow][quad * 8];
            bf16x8 ax1 = *(const bf16x8*)&X[mrow][32 + quad * 8];
            f32x4 gh[3], gi[3];
#pragma unroll
            for (int g = 0; g < 3; ++g) {
                f32x4 acc = {0.f, 0.f, 0.f, 0.f};
                acc = __builtin_amdgcn_mfma_f32_16x16x32_bf16(ah0, Bh[g][0], acc, 0, 0, 0);
                acc = __builtin_amdgcn_mfma_f32_16x16x32_bf16(ah1, Bh[g][1], acc, 0, 0, 0);
                gh[g] = acc;
                f32x4 acc2 = {0.f, 0.f, 0.f, 0.f};
                acc2 = __builtin_amdgcn_mfma_f32_16x16x32_bf16(ax0, Bi[g][0], acc2, 0, 0, 0);
                acc2 = __builtin_amdgcn_mfma_f32_16x16x32_bf16(ax1, Bi[g][1], acc2, 0, 0, 0);
                gi[g] = acc2;
            }
            ushort_t hnb[4];
#pragma unroll
            for (int rg = 0; rg < 4; ++rg) {
                float r = sigm(bi[0] + gi[0][rg] + bh[0] + gh[0][rg]);
                float z = sigm(bi[1] + gi[1][rg] + bh[1] + gh[1][rg]);
                float n = tanh_fast(bi[2] + gi[2][rg] + r * (bh[2] + gh[2][rg]));
                float hv = (1.f - z) * n + z * hold[mt][rg];
                hold[mt][rg] = hv;
                hnb[rg] = fbf(hv);
            }
            __syncthreads();   // B
#pragma unroll
            for (int rg = 0; rg < 4; ++rg) {
                const int sloc = mw * 32 + mt * 16 + quad * 4 + rg;
                H[sloc][j] = hnb[rg];
            }
        }
    }
#pragma unroll
    for (int mt = 0; mt < 2; ++mt)
#pragma unroll
        for (int rg = 0; rg < 4; ++rg) {
            const int sloc = mw * 32 + mt * 16 + quad * 4 + rg;
            h2out[(s0 + sloc) * HDIM + j] = hold[mt][rg];
        }
}

extern "C" void kernel_launch(void* const* d_in, const int* in_sizes, int n_in,
                              void* d_out, int out_size, void* d_ws, size_t ws_size,
                              hipStream_t stream)
{
    const float* data     = (const float*)d_in[0];
    const float* features = (const float*)d_in[1];
    const int*   edges    = (const int*)d_in[2];
    const float* Wih1     = (const float*)d_in[3];
    const float* Whh1     = (const float*)d_in[4];
    const float* bih1     = (const float*)d_in[5];
    const float* bhh1     = (const float*)d_in[6];
    const float* W1       = (const float*)d_in[7];
    const float* b1       = (const float*)d_in[8];
    const float* W2       = (const float*)d_in[9];
    const float* b2       = (const float*)d_in[10];
    const float* W3       = (const float*)d_in[11];
    const float* b3       = (const float*)d_in[12];
    const float* Wih2     = (const float*)d_in[13];
    const float* Whh2     = (const float*)d_in[14];
    const float* bih2     = (const float*)d_in[15];
    const float* bhh2     = (const float*)d_in[16];

    float*    out  = (float*)d_out;
    char*     ws   = (char*)d_ws;
    ushort_t* out1 = (ushort_t*)ws;                    // bf16 intermediate
    float*    agg  = (float*)(ws + OUT1_BYTES);        // fp32 GAT output
    int*      meta = (int*)(ws + OUT1_BYTES + AGG_BYTES);
    int* degree   = meta;                // [2000]
    int* cursor   = meta + NNODE;        // [2000]
    int* rowstart = meta + 2 * NNODE;    // [2000]
    int* srcids   = meta + 3 * NNODE;    // [16000]

    hipMemsetAsync(meta, 0, 2 * NNODE * sizeof(int), stream);   // degree+cursor

    count_kernel<<<(NEDGE + 255) / 256, 256, 0, stream>>>(edges, degree);
    scan_kernel<<<1, 256, 0, stream>>>(degree, rowstart);
    scatter_kernel<<<(NEDGE + 255) / 256, 256, 0, stream>>>(edges, rowstart, cursor, srcids);

    gru1_kernel<<<NSEQ / 64, 512, 0, stream>>>(data, Wih1, Whh1, bih1, bhh1, out1, out);
    gat_csr_kernel<<<NNODE, 256, 0, stream>>>(out1, features, degree, rowstart, srcids,
                                              W1, b1, W2, b2, W3, b3, agg);
    gru2_kernel<<<NSEQ / 64, 512, 0, stream>>>(agg, Wih2, Whh2, bih2, bhh2,
                                               out + NNODE * NB * HDIM);
}

// Round 7
// 364.493 us; speedup vs baseline: 6.9552x; 1.0391x over previous
//
#include <hip/hip_runtime.h>

typedef unsigned short ushort_t;
typedef unsigned int uint_t;
typedef __attribute__((ext_vector_type(8))) short bf16x8;
typedef __attribute__((ext_vector_type(4))) float f32x4;

#define NNODE 2000
#define NB 8
#define LSEQ 12
#define HDIM 64
#define NEDGE 16000
#define NSEQ (NNODE * NB)            // 16000 sequences
#define OUT1_ELEMS (NNODE * NB * LSEQ * HDIM)   // 12,288,000
#define OUT1_BYTES (OUT1_ELEMS * 2)             // bf16 intermediate: 24,576,000
#define AGG_BYTES  (OUT1_ELEMS * 4)             // fp32: 49,152,000

__device__ __forceinline__ float bf1(ushort_t u) { return __uint_as_float(((uint_t)u) << 16); }
__device__ __forceinline__ ushort_t fbf(float f) {
    uint_t x = __float_as_uint(f);
    uint_t r = x + 0x7fffu + ((x >> 16) & 1u);   // RNE
    return (ushort_t)(r >> 16);
}
__device__ __forceinline__ float sigm(float x) { return 1.f / (1.f + __expf(-x)); }
__device__ __forceinline__ float tanh_fast(float x) { return 2.f / (1.f + __expf(-2.f * x)) - 1.f; }

// ===========================================================================
// MFMA geometry (HW-verified R3): A[m=lane&15][k=quad*8+jj];
// B[k=ks*32+quad*8+jj][n=lane&15]; C row(M)=quad*4+reg, col(N)=lane&15.
// ===========================================================================

// ---------------------------------------------------------------------------
// GRU1: x_t is only 2-wide -> gi on VALU; gh via MFMA. out1 bf16 per step.
// ---------------------------------------------------------------------------
__global__ __launch_bounds__(512, 2) void gru1_kernel(
    const float* __restrict__ data, const float* __restrict__ Wih,
    const float* __restrict__ Whh, const float* __restrict__ bih,
    const float* __restrict__ bhh, ushort_t* __restrict__ out1,
    float* __restrict__ h1out)
{
    __shared__ ushort_t H[64][72] __attribute__((aligned(16)));  // 9216 B
    __shared__ float XD[64][26];                                 // 6656 B

    const int tid = threadIdx.x;
    const int wv = tid >> 6;
    const int mw = wv & 1, nw = wv >> 1;
    const int c = tid & 15;
    const int quad = (tid >> 4) & 3;
    const int j = nw * 16 + c;
    const int s0 = blockIdx.x * 64;

    *(uint4*)&H[tid & 63][(tid >> 6) * 8] = uint4{0, 0, 0, 0};
#pragma unroll
    for (int p = 0; p < 3; ++p) {
        const int flat = p * 512 + tid;     // 0..1535
        const int sl = flat / 24, q = flat - sl * 24;
        XD[sl][q] = data[(s0 + sl) * 24 + q];
    }

    bf16x8 Bh[3][2];
    float wi0[3], wi1[3], bi[3], bh[3];
#pragma unroll
    for (int g = 0; g < 3; ++g) {
        const int row = g * 64 + j;
        float2 wi = *(const float2*)(Wih + row * 2);
        wi0[g] = wi.x; wi1[g] = wi.y;
        bi[g] = bih[row]; bh[g] = bhh[row];
#pragma unroll
        for (int ks = 0; ks < 2; ++ks) {
            const float* wp = Whh + (row << 6) + ks * 32 + quad * 8;
            float4 wa = *(const float4*)wp;
            float4 wb = *(const float4*)(wp + 4);
            ushort_t tmp[8];
            tmp[0] = fbf(wa.x); tmp[1] = fbf(wa.y); tmp[2] = fbf(wa.z); tmp[3] = fbf(wa.w);
            tmp[4] = fbf(wb.x); tmp[5] = fbf(wb.y); tmp[6] = fbf(wb.z); tmp[7] = fbf(wb.w);
            Bh[g][ks] = *(bf16x8*)tmp;
        }
    }

    float hold[2][4];
#pragma unroll
    for (int mt = 0; mt < 2; ++mt)
#pragma unroll
        for (int rg = 0; rg < 4; ++rg) hold[mt][rg] = 0.f;

    for (int t = 0; t < LSEQ; ++t) {
        __syncthreads();   // A: H (+XD at t=0) visible
#pragma unroll
        for (int mt = 0; mt < 2; ++mt) {
            bf16x8 a0 = *(const bf16x8*)&H[mw * 32 + mt * 16 + c][quad * 8];
            bf16x8 a1 = *(const bf16x8*)&H[mw * 32 + mt * 16 + c][32 + quad * 8];
            f32x4 gh[3];
#pragma unroll
            for (int g = 0; g < 3; ++g) {
                f32x4 acc = {0.f, 0.f, 0.f, 0.f};
                acc = __builtin_amdgcn_mfma_f32_16x16x32_bf16(a0, Bh[g][0], acc, 0, 0, 0);
                acc = __builtin_amdgcn_mfma_f32_16x16x32_bf16(a1, Bh[g][1], acc, 0, 0, 0);
                gh[g] = acc;
            }
            ushort_t hnb[4];
#pragma unroll
            for (int rg = 0; rg < 4; ++rg) {
                const int sloc = mw * 32 + mt * 16 + quad * 4 + rg;
                float2 xp = *(const float2*)&XD[sloc][2 * t];
                float gr = bh[0] + gh[0][rg];
                float gz = bh[1] + gh[1][rg];
                float gn = bh[2] + gh[2][rg];
                float ir = bi[0] + wi0[0] * xp.x + wi1[0] * xp.y;
                float iz = bi[1] + wi0[1] * xp.x + wi1[1] * xp.y;
                float in = bi[2] + wi0[2] * xp.x + wi1[2] * xp.y;
                float r = sigm(ir + gr);
                float z = sigm(iz + gz);
                float n = tanh_fast(in + r * gn);
                float hv = (1.f - z) * n + z * hold[mt][rg];
                hold[mt][rg] = hv;
                hnb[rg] = fbf(hv);
            }
            __syncthreads();   // B
#pragma unroll
            for (int rg = 0; rg < 4; ++rg) {
                const int sloc = mw * 32 + mt * 16 + quad * 4 + rg;
                H[sloc][j] = hnb[rg];
                out1[(s0 + sloc) * (LSEQ * HDIM) + t * HDIM + j] = hnb[rg];
            }
        }
    }
#pragma unroll
    for (int mt = 0; mt < 2; ++mt)
#pragma unroll
        for (int rg = 0; rg < 4; ++rg) {
            const int sloc = mw * 32 + mt * 16 + quad * 4 + rg;
            h1out[(s0 + sloc) * HDIM + j] = hold[mt][rg];
        }
}

// ---------------------------------------------------------------------------
// CSR helpers: degree histogram -> single-block scan -> scatter src+edge ids.
// ---------------------------------------------------------------------------
__global__ __launch_bounds__(256) void count_kernel(const int* __restrict__ edges,
                                                    int* __restrict__ degree)
{
    const int e = blockIdx.x * 256 + threadIdx.x;
    if (e < NEDGE) atomicAdd(&degree[edges[NEDGE + e]], 1);
}

__global__ __launch_bounds__(256) void scan_kernel(const int* __restrict__ degree,
                                                   int* __restrict__ rowstart)
{
    __shared__ int part[256];
    const int t = threadIdx.x;
    const int base = t * 8;
    int s = 0;
#pragma unroll
    for (int q = 0; q < 8; ++q) { const int idx = base + q; if (idx < NNODE) s += degree[idx]; }
    part[t] = s;
    __syncthreads();
    if (t == 0) {
        int run = 0;
        for (int u = 0; u < 256; ++u) { const int v = part[u]; part[u] = run; run += v; }
    }
    __syncthreads();
    int run = part[t];
#pragma unroll
    for (int q = 0; q < 8; ++q) {
        const int idx = base + q;
        if (idx < NNODE) { rowstart[idx] = run; run += degree[idx]; }
    }
}

__global__ __launch_bounds__(256) void scatter_kernel(const int* __restrict__ edges,
                                                      const int* __restrict__ rowstart,
                                                      int* __restrict__ cursor,
                                                      int* __restrict__ srcids,
                                                      int* __restrict__ eids)
{
    const int e = blockIdx.x * 256 + threadIdx.x;
    if (e < NEDGE) {
        const int d = edges[NEDGE + e];
        const int pos = atomicAdd(&cursor[d], 1);
        srcids[rowstart[d] + pos] = edges[e];   // src node
        eids[rowstart[d] + pos] = e;            // edge id (alpha index)
    }
}

// ---------------------------------------------------------------------------
// Per-edge MLP hoisted out of the GAT loop: alphas[2e] = (a0,a1) for all
// 18000 edges (incl. self loops e>=NEDGE). One wave per edge.
// ---------------------------------------------------------------------------
__global__ __launch_bounds__(256) void alpha_kernel(
    const float* __restrict__ features, const int* __restrict__ edges,
    const float* __restrict__ W1, const float* __restrict__ b1,
    const float* __restrict__ W2, const float* __restrict__ b2,
    float* __restrict__ alphas)
{
    __shared__ float m1[4][16];
    const int tid = threadIdx.x;
    const int w = tid >> 6, lane = tid & 63;
    const int e = blockIdx.x * 4 + w;           // grid sized exactly 18000/4
    int i, j;
    if (e < NEDGE) { j = edges[e]; i = edges[NEDGE + e]; }
    else { i = j = e - NEDGE; }

    const int o = lane >> 2, q = lane & 3;      // 16 outputs x 4 partials
    const float* fsrc = (q < 2) ? (features + i * 64 + q * 32)
                                : (features + j * 64 + (q - 2) * 32);
    const float* wsrc = W1 + o * 128 + q * 32;
    float acc = 0.f;
#pragma unroll
    for (int k = 0; k < 32; ++k) acc += fsrc[k] * wsrc[k];
    acc += __shfl_xor(acc, 1);
    acc += __shfl_xor(acc, 2);
    if (q == 0) m1[w][o] = sigm(acc + b1[o]);
    __syncthreads();
    if (lane < 32) {
        const int o2 = lane >> 4, k = lane & 15;
        float p = m1[w][k] * W2[o2 * 16 + k];
        p += __shfl_xor(p, 1);
        p += __shfl_xor(p, 2);
        p += __shfl_xor(p, 4);
        p += __shfl_xor(p, 8);
        if (k == 0) alphas[e * 2 + o2] = sigm(p + b2[o2]);
    }
}

// ---------------------------------------------------------------------------
// MetaGAT (CSR, MFMA, pipelined): 2 blocks per dst node (M-halves: 48 of 96
// rows). states_i half staged once; states_j half double-streamed through
// registers (prefetch next edge under current edge's MFMAs). Alphas
// precomputed. W3/b3 pinned in VGPRs. Row stride 140 (70 dw = 6 mod 32):
// conflict-free-ish A-frag reads. No atomics.
// ---------------------------------------------------------------------------
__global__ __launch_bounds__(256) void gat_csr_kernel(
    const ushort_t* __restrict__ out1,
    const int* __restrict__ degree, const int* __restrict__ rowstart,
    const int* __restrict__ srcids, const int* __restrict__ eids,
    const float* __restrict__ alphas,
    const float* __restrict__ W3, const float* __restrict__ b3,
    float* __restrict__ agg)
{
    __shared__ ushort_t S[48][140] __attribute__((aligned(16)));   // 13440 B

    const int tid = threadIdx.x;
    const int i = blockIdx.x >> 1;
    const int mh = blockIdx.x & 1;        // M-half: rows [48*mh, 48*mh+48)
    const int deg = degree[i];
    const int rs = rowstart[i];

    const int wv = tid >> 6;              // N-strip
    const int r = tid & 15;
    const int quad = (tid >> 4) & 3;
    const int n = wv * 16 + r;

    const ushort_t* pi = out1 + i * (NB * LSEQ * HDIM);

    // ---- stage states_i half (cols 0..63): 48 rows x 8 b128 chunks ----
#pragma unroll
    for (int p = 0; p < 2; ++p) {
        const int u = tid + p * 256;
        if (u < 384) {
            const int rr = u >> 3, c = u & 7;
            const int b = rr & 7, l = (rr >> 3) + 6 * mh;   // row = l*8+b
            *(uint4*)&S[rr][c * 8] = *(const uint4*)(pi + (b * 12 + l) * 64 + c * 8);
        }
    }

    // ---- pin W3/b3 in registers ----
    float w3a[32], w3b[32], w3c[32];
#pragma unroll
    for (int ks = 0; ks < 4; ++ks)
#pragma unroll
        for (int jj = 0; jj < 8; ++jj) {
            const int m = (ks * 32 + quad * 8 + jj) * 64 + n;
            float2 w2 = ((const float2*)W3)[m];
            w3a[ks * 8 + jj] = w2.x; w3b[ks * 8 + jj] = w2.y; w3c[ks * 8 + jj] = b3[m];
        }

    float accN[3][4];
#pragma unroll
    for (int mt = 0; mt < 3; ++mt)
#pragma unroll
        for (int g2 = 0; g2 < 4; ++g2) accN[mt][g2] = 0.f;

    // ---- prefetch self-loop (edge 0) j-states: 48 rows x 16 uint2 = 768 ----
    uint2 pf[3];
#pragma unroll
    for (int p = 0; p < 3; ++p) {
        const int u = p * 256 + tid;
        const int rr = u >> 4, c4 = u & 15;
        const int b = rr & 7, l = (rr >> 3) + 6 * mh;
        pf[p] = *(const uint2*)(pi + (b * 12 + l) * 64 + c4 * 4);
    }

    for (int eo = 0; eo <= deg; ++eo) {
        __syncthreads();   // prior reads of j-half done (and S_i staged at eo=0)
#pragma unroll
        for (int p = 0; p < 3; ++p) {
            const int u = p * 256 + tid;
            const int rr = u >> 4, c4 = u & 15;
            *(uint2*)&S[rr][64 + c4 * 4] = pf[p];
        }
        const int eid = (eo == 0) ? (NEDGE + i) : eids[rs + eo - 1];
        const float2 a01 = *(const float2*)(alphas + eid * 2);
        const int jn = (eo < deg) ? srcids[rs + eo] : 0;
        __syncthreads();   // j-half ready

        // prefetch next edge's j-states under this edge's compute
        if (eo < deg) {
            const ushort_t* pj = out1 + jn * (NB * LSEQ * HDIM);
#pragma unroll
            for (int p = 0; p < 3; ++p) {
                const int u = p * 256 + tid;
                const int rr = u >> 4, c4 = u & 15;
                const int b = rr & 7, l = (rr >> 3) + 6 * mh;
                pf[p] = *(const uint2*)(pj + (b * 12 + l) * 64 + c4 * 4);
            }
        }

        // B-fragments from pinned registers
        bf16x8 bfrag[4];
#pragma unroll
        for (int ks = 0; ks < 4; ++ks) {
            ushort_t tmp[8];
#pragma unroll
            for (int jj = 0; jj < 8; ++jj) {
                const int q = ks * 8 + jj;
                tmp[jj] = fbf(fmaf(a01.y, w3b[q], fmaf(a01.x, w3a[q], w3c[q])));
            }
            bfrag[ks] = *(bf16x8*)tmp;
        }

#pragma unroll
        for (int mt = 0; mt < 3; ++mt) {
            f32x4 acc = {0.f, 0.f, 0.f, 0.f};
#pragma unroll
            for (int ks = 0; ks < 4; ++ks) {
                bf16x8 afrag = *(const bf16x8*)&S[mt * 16 + r][ks * 32 + quad * 8];
                acc = __builtin_amdgcn_mfma_f32_16x16x32_bf16(afrag, bfrag[ks], acc, 0, 0, 0);
            }
            float v[4];
#pragma unroll
            for (int g2 = 0; g2 < 4; ++g2) {
                float x = acc[g2];
                v[g2] = x > 0.f ? x : 0.01f * x;   // leaky_relu
            }
            float mx = fmaxf(fmaxf(v[0], v[1]), fmaxf(v[2], v[3]));
            mx = fmaxf(mx, __shfl_xor(mx, 16));
            float s = 0.f;
#pragma unroll
            for (int g2 = 0; g2 < 4; ++g2) { v[g2] = __expf(v[g2] - mx); s += v[g2]; }
            s += __shfl_xor(s, 16);
            const float inv = 1.f / s;
#pragma unroll
            for (int g2 = 0; g2 < 4; ++g2) {
                const int lr = mt * 16 + quad * 4 + g2;
                accN[mt][g2] += v[g2] * inv * bf1(S[lr][64 + n]);
            }
        }
    }

    // single non-atomic store of this half-node's aggregate
#pragma unroll
    for (int mt = 0; mt < 3; ++mt)
#pragma unroll
        for (int g2 = 0; g2 < 4; ++g2) {
            const int gr = 48 * mh + mt * 16 + quad * 4 + g2;  // = l*8 + b
            const int b = gr & 7, l = gr >> 3;
            agg[(i * 96 + b * 12 + l) * 64 + n] = accN[mt][g2];
        }
}

// ---------------------------------------------------------------------------
// GRU2: gi AND gh via MFMA; x_t = relu(agg) staged bf16, next-step global
// load software-pipelined under the MFMAs.
// ---------------------------------------------------------------------------
__global__ __launch_bounds__(512, 2) void gru2_kernel(
    const float* __restrict__ agg, const float* __restrict__ Wih,
    const float* __restrict__ Whh, const float* __restrict__ bih,
    const float* __restrict__ bhh, float* __restrict__ h2out)
{
    __shared__ ushort_t H[64][72] __attribute__((aligned(16)));  // 9216 B
    __shared__ ushort_t X[64][72] __attribute__((aligned(16)));  // 9216 B

    const int tid = threadIdx.x;
    const int wv = tid >> 6;
    const int mw = wv & 1, nw = wv >> 1;
    const int c = tid & 15;
    const int quad = (tid >> 4) & 3;
    const int j = nw * 16 + c;
    const int s0 = blockIdx.x * 64;
    const int sl = tid >> 3, k0 = (tid & 7) * 8;

    *(uint4*)&H[tid & 63][(tid >> 6) * 8] = uint4{0, 0, 0, 0};

    bf16x8 Bh[3][2], Bi[3][2];
    float bi[3], bh[3];
#pragma unroll
    for (int g = 0; g < 3; ++g) {
        const int row = g * 64 + j;
        bi[g] = bih[row]; bh[g] = bhh[row];
#pragma unroll
        for (int ks = 0; ks < 2; ++ks) {
            const float* wp = Whh + (row << 6) + ks * 32 + quad * 8;
            float4 wa = *(const float4*)wp;
            float4 wb = *(const float4*)(wp + 4);
            ushort_t tmp[8];
            tmp[0] = fbf(wa.x); tmp[1] = fbf(wa.y); tmp[2] = fbf(wa.z); tmp[3] = fbf(wa.w);
            tmp[4] = fbf(wb.x); tmp[5] = fbf(wb.y); tmp[6] = fbf(wb.z); tmp[7] = fbf(wb.w);
            Bh[g][ks] = *(bf16x8*)tmp;
            const float* wp2 = Wih + (row << 6) + ks * 32 + quad * 8;
            float4 va = *(const float4*)wp2;
            float4 vb = *(const float4*)(wp2 + 4);
            tmp[0] = fbf(va.x); tmp[1] = fbf(va.y); tmp[2] = fbf(va.z); tmp[3] = fbf(va.w);
            tmp[4] = fbf(vb.x); tmp[5] = fbf(vb.y); tmp[6] = fbf(vb.z); tmp[7] = fbf(vb.w);
            Bi[g][ks] = *(bf16x8*)tmp;
        }
    }

    float hold[2][4];
#pragma unroll
    for (int mt = 0; mt < 2; ++mt)
#pragma unroll
        for (int rg = 0; rg < 4; ++rg) hold[mt][rg] = 0.f;

    float xr[8];
    {
        const float* gp = agg + (s0 + sl) * (LSEQ * HDIM) + k0;
        *(float4*)&xr[0] = *(const float4*)gp;
        *(float4*)&xr[4] = *(const float4*)(gp + 4);
    }

    for (int t = 0; t < LSEQ; ++t) {
        {
            ushort_t xs[8];
#pragma unroll
            for (int q = 0; q < 8; ++q) xs[q] = fbf(xr[q] > 0.f ? xr[q] : 0.f);
            *(uint4*)&X[sl][k0] = *(uint4*)xs;
        }
        __syncthreads();   // A: X_t + H_t visible
        if (t < LSEQ - 1) {
            const float* gp = agg + (s0 + sl) * (LSEQ * HDIM) + (t + 1) * HDIM + k0;
            *(float4*)&xr[0] = *(const float4*)gp;
            *(float4*)&xr[4] = *(const float4*)(gp + 4);
        }
#pragma unroll
        for (int mt = 0; mt < 2; ++mt) {
            const int mrow = mw * 32 + mt * 16 + c;
            bf16x8 ah0 = *(const bf16x8*)&H[mrow][quad * 8];
            bf16x8 ah1 = *(const bf16x8*)&H[mrow][32 + quad * 8];
            bf16x8 ax0 = *(const bf16x8*)&X[mrow][quad * 8];
            bf16x8 ax1 = *(const bf16x8*)&X[mrow][32 + quad * 8];
            f32x4 gh[3], gi[3];
#pragma unroll
            for (int g = 0; g < 3; ++g) {
                f32x4 acc = {0.f, 0.f, 0.f, 0.f};
                acc = __builtin_amdgcn_mfma_f32_16x16x32_bf16(ah0, Bh[g][0], acc, 0, 0, 0);
                acc = __builtin_amdgcn_mfma_f32_16x16x32_bf16(ah1, Bh[g][1], acc, 0, 0, 0);
                gh[g] = acc;
                f32x4 acc2 = {0.f, 0.f, 0.f, 0.f};
                acc2 = __builtin_amdgcn_mfma_f32_16x16x32_bf16(ax0, Bi[g][0], acc2, 0, 0, 0);
                acc2 = __builtin_amdgcn_mfma_f32_16x16x32_bf16(ax1, Bi[g][1], acc2, 0, 0, 0);
                gi[g] = acc2;
            }
            ushort_t hnb[4];
#pragma unroll
            for (int rg = 0; rg < 4; ++rg) {
                float r = sigm(bi[0] + gi[0][rg] + bh[0] + gh[0][rg]);
                float z = sigm(bi[1] + gi[1][rg] + bh[1] + gh[1][rg]);
                float n = tanh_fast(bi[2] + gi[2][rg] + r * (bh[2] + gh[2][rg]));
                float hv = (1.f - z) * n + z * hold[mt][rg];
                hold[mt][rg] = hv;
                hnb[rg] = fbf(hv);
            }
            __syncthreads();   // B
#pragma unroll
            for (int rg = 0; rg < 4; ++rg) {
                const int sloc = mw * 32 + mt * 16 + quad * 4 + rg;
                H[sloc][j] = hnb[rg];
            }
        }
    }
#pragma unroll
    for (int mt = 0; mt < 2; ++mt)
#pragma unroll
        for (int rg = 0; rg < 4; ++rg) {
            const int sloc = mw * 32 + mt * 16 + quad * 4 + rg;
            h2out[(s0 + sloc) * HDIM + j] = hold[mt][rg];
        }
}

extern "C" void kernel_launch(void* const* d_in, const int* in_sizes, int n_in,
                              void* d_out, int out_size, void* d_ws, size_t ws_size,
                              hipStream_t stream)
{
    const float* data     = (const float*)d_in[0];
    const float* features = (const float*)d_in[1];
    const int*   edges    = (const int*)d_in[2];
    const float* Wih1     = (const float*)d_in[3];
    const float* Whh1     = (const float*)d_in[4];
    const float* bih1     = (const float*)d_in[5];
    const float* bhh1     = (const float*)d_in[6];
    const float* W1       = (const float*)d_in[7];
    const float* b1       = (const float*)d_in[8];
    const float* W2       = (const float*)d_in[9];
    const float* b2       = (const float*)d_in[10];
    const float* W3       = (const float*)d_in[11];
    const float* b3       = (const float*)d_in[12];
    const float* Wih2     = (const float*)d_in[13];
    const float* Whh2     = (const float*)d_in[14];
    const float* bih2     = (const float*)d_in[15];
    const float* bhh2     = (const float*)d_in[16];

    float*    out  = (float*)d_out;
    char*     ws   = (char*)d_ws;
    ushort_t* out1 = (ushort_t*)ws;                    // bf16 intermediate
    float*    agg  = (float*)(ws + OUT1_BYTES);        // fp32 GAT output
    int*      meta = (int*)(ws + OUT1_BYTES + AGG_BYTES);
    int*   degree   = meta;                       // [2000]
    int*   cursor   = meta + NNODE;               // [2000]
    int*   rowstart = meta + 2 * NNODE;           // [2000]
    int*   srcids   = meta + 3 * NNODE;           // [16000]
    int*   eids     = meta + 3 * NNODE + NEDGE;   // [16000]
    float* alphas   = (float*)(meta + 3 * NNODE + 2 * NEDGE);  // [36000]

    hipMemsetAsync(meta, 0, 2 * NNODE * sizeof(int), stream);   // degree+cursor

    count_kernel<<<(NEDGE + 255) / 256, 256, 0, stream>>>(edges, degree);
    scan_kernel<<<1, 256, 0, stream>>>(degree, rowstart);
    scatter_kernel<<<(NEDGE + 255) / 256, 256, 0, stream>>>(edges, rowstart, cursor,
                                                            srcids, eids);
    alpha_kernel<<<(NEDGE + NNODE) / 4, 256, 0, stream>>>(features, edges,
                                                          W1, b1, W2, b2, alphas);

    gru1_kernel<<<NSEQ / 64, 512, 0, stream>>>(data, Wih1, Whh1, bih1, bhh1, out1, out);
    gat_csr_kernel<<<2 * NNODE, 256, 0, stream>>>(out1, degree, rowstart, srcids, eids,
                                                  alphas, W3, b3, agg);
    gru2_kernel<<<NSEQ / 64, 512, 0, stream>>>(agg, Wih2, Whh2, bih2, bhh2,
                                               out + NNODE * NB * HDIM);
}

// Round 8
// 352.428 us; speedup vs baseline: 7.1933x; 1.0342x over previous
//
#include <hip/hip_runtime.h>

typedef unsigned short ushort_t;
typedef unsigned int uint_t;
typedef __attribute__((ext_vector_type(8))) short bf16x8;
typedef __attribute__((ext_vector_type(4))) float f32x4;

#define NNODE 2000
#define NB 8
#define LSEQ 12
#define HDIM 64
#define NEDGE 16000
#define NSEQ (NNODE * NB)            // 16000 sequences
#define OUT1_ELEMS (NNODE * NB * LSEQ * HDIM)   // 12,288,000
#define OUT1_BYTES (OUT1_ELEMS * 2)             // bf16 intermediate: 24,576,000
#define AGG_BYTES  (OUT1_ELEMS * 4)             // fp32: 49,152,000

__device__ __forceinline__ float bf1(ushort_t u) { return __uint_as_float(((uint_t)u) << 16); }
__device__ __forceinline__ ushort_t fbf(float f) {
    uint_t x = __float_as_uint(f);
    uint_t r = x + 0x7fffu + ((x >> 16) & 1u);   // RNE
    return (ushort_t)(r >> 16);
}
__device__ __forceinline__ float sigm(float x) { return 1.f / (1.f + __expf(-x)); }
__device__ __forceinline__ float tanh_fast(float x) { return 2.f / (1.f + __expf(-2.f * x)) - 1.f; }

// ===========================================================================
// MFMA geometry (HW-verified R3): A[m=lane&15][k=quad*8+jj];
// B[k=ks*32+quad*8+jj][n=lane&15]; C row(M)=quad*4+reg, col(N)=lane&15.
// ===========================================================================

// ---------------------------------------------------------------------------
// GRU1: x_t is only 2-wide -> gi on VALU; gh via MFMA. out1 bf16 per step.
// ---------------------------------------------------------------------------
__global__ __launch_bounds__(512, 2) void gru1_kernel(
    const float* __restrict__ data, const float* __restrict__ Wih,
    const float* __restrict__ Whh, const float* __restrict__ bih,
    const float* __restrict__ bhh, ushort_t* __restrict__ out1,
    float* __restrict__ h1out)
{
    __shared__ ushort_t H[64][72] __attribute__((aligned(16)));  // 9216 B
    __shared__ float XD[64][26];                                 // 6656 B

    const int tid = threadIdx.x;
    const int wv = tid >> 6;
    const int mw = wv & 1, nw = wv >> 1;
    const int c = tid & 15;
    const int quad = (tid >> 4) & 3;
    const int j = nw * 16 + c;
    const int s0 = blockIdx.x * 64;

    *(uint4*)&H[tid & 63][(tid >> 6) * 8] = uint4{0, 0, 0, 0};
#pragma unroll
    for (int p = 0; p < 3; ++p) {
        const int flat = p * 512 + tid;     // 0..1535
        const int sl = flat / 24, q = flat - sl * 24;
        XD[sl][q] = data[(s0 + sl) * 24 + q];
    }

    bf16x8 Bh[3][2];
    float wi0[3], wi1[3], bi[3], bh[3];
#pragma unroll
    for (int g = 0; g < 3; ++g) {
        const int row = g * 64 + j;
        float2 wi = *(const float2*)(Wih + row * 2);
        wi0[g] = wi.x; wi1[g] = wi.y;
        bi[g] = bih[row]; bh[g] = bhh[row];
#pragma unroll
        for (int ks = 0; ks < 2; ++ks) {
            const float* wp = Whh + (row << 6) + ks * 32 + quad * 8;
            float4 wa = *(const float4*)wp;
            float4 wb = *(const float4*)(wp + 4);
            ushort_t tmp[8];
            tmp[0] = fbf(wa.x); tmp[1] = fbf(wa.y); tmp[2] = fbf(wa.z); tmp[3] = fbf(wa.w);
            tmp[4] = fbf(wb.x); tmp[5] = fbf(wb.y); tmp[6] = fbf(wb.z); tmp[7] = fbf(wb.w);
            Bh[g][ks] = *(bf16x8*)tmp;
        }
    }

    float hold[2][4];
#pragma unroll
    for (int mt = 0; mt < 2; ++mt)
#pragma unroll
        for (int rg = 0; rg < 4; ++rg) hold[mt][rg] = 0.f;

    for (int t = 0; t < LSEQ; ++t) {
        __syncthreads();   // A: H (+XD at t=0) visible
#pragma unroll
        for (int mt = 0; mt < 2; ++mt) {
            bf16x8 a0 = *(const bf16x8*)&H[mw * 32 + mt * 16 + c][quad * 8];
            bf16x8 a1 = *(const bf16x8*)&H[mw * 32 + mt * 16 + c][32 + quad * 8];
            f32x4 gh[3];
#pragma unroll
            for (int g = 0; g < 3; ++g) {
                f32x4 acc = {0.f, 0.f, 0.f, 0.f};
                acc = __builtin_amdgcn_mfma_f32_16x16x32_bf16(a0, Bh[g][0], acc, 0, 0, 0);
                acc = __builtin_amdgcn_mfma_f32_16x16x32_bf16(a1, Bh[g][1], acc, 0, 0, 0);
                gh[g] = acc;
            }
            ushort_t hnb[4];
#pragma unroll
            for (int rg = 0; rg < 4; ++rg) {
                const int sloc = mw * 32 + mt * 16 + quad * 4 + rg;
                float2 xp = *(const float2*)&XD[sloc][2 * t];
                float gr = bh[0] + gh[0][rg];
                float gz = bh[1] + gh[1][rg];
                float gn = bh[2] + gh[2][rg];
                float ir = bi[0] + wi0[0] * xp.x + wi1[0] * xp.y;
                float iz = bi[1] + wi0[1] * xp.x + wi1[1] * xp.y;
                float in = bi[2] + wi0[2] * xp.x + wi1[2] * xp.y;
                float r = sigm(ir + gr);
                float z = sigm(iz + gz);
                float n = tanh_fast(in + r * gn);
                float hv = (1.f - z) * n + z * hold[mt][rg];
                hold[mt][rg] = hv;
                hnb[rg] = fbf(hv);
            }
            __syncthreads();   // B
#pragma unroll
            for (int rg = 0; rg < 4; ++rg) {
                const int sloc = mw * 32 + mt * 16 + quad * 4 + rg;
                H[sloc][j] = hnb[rg];
                out1[(s0 + sloc) * (LSEQ * HDIM) + t * HDIM + j] = hnb[rg];
            }
        }
    }
#pragma unroll
    for (int mt = 0; mt < 2; ++mt)
#pragma unroll
        for (int rg = 0; rg < 4; ++rg) {
            const int sloc = mw * 32 + mt * 16 + quad * 4 + rg;
            h1out[(s0 + sloc) * HDIM + j] = hold[mt][rg];
        }
}

// ---------------------------------------------------------------------------
// CSR helpers: degree histogram -> single-block scan -> scatter src+edge ids.
// ---------------------------------------------------------------------------
__global__ __launch_bounds__(256) void count_kernel(const int* __restrict__ edges,
                                                    int* __restrict__ degree)
{
    const int e = blockIdx.x * 256 + threadIdx.x;
    if (e < NEDGE) atomicAdd(&degree[edges[NEDGE + e]], 1);
}

__global__ __launch_bounds__(256) void scan_kernel(const int* __restrict__ degree,
                                                   int* __restrict__ rowstart)
{
    __shared__ int part[256];
    const int t = threadIdx.x;
    const int base = t * 8;
    int s = 0;
#pragma unroll
    for (int q = 0; q < 8; ++q) { const int idx = base + q; if (idx < NNODE) s += degree[idx]; }
    part[t] = s;
    __syncthreads();
    if (t == 0) {
        int run = 0;
        for (int u = 0; u < 256; ++u) { const int v = part[u]; part[u] = run; run += v; }
    }
    __syncthreads();
    int run = part[t];
#pragma unroll
    for (int q = 0; q < 8; ++q) {
        const int idx = base + q;
        if (idx < NNODE) { rowstart[idx] = run; run += degree[idx]; }
    }
}

__global__ __launch_bounds__(256) void scatter_kernel(const int* __restrict__ edges,
                                                      const int* __restrict__ rowstart,
                                                      int* __restrict__ cursor,
                                                      int* __restrict__ srcids,
                                                      int* __restrict__ eids)
{
    const int e = blockIdx.x * 256 + threadIdx.x;
    if (e < NEDGE) {
        const int d = edges[NEDGE + e];
        const int pos = atomicAdd(&cursor[d], 1);
        srcids[rowstart[d] + pos] = edges[e];   // src node
        eids[rowstart[d] + pos] = e;            // edge id (alpha index)
    }
}

// ---------------------------------------------------------------------------
// Per-edge MLP hoisted: alphas[2e] = (a0,a1), all 18000 edges incl. self.
// ---------------------------------------------------------------------------
__global__ __launch_bounds__(256) void alpha_kernel(
    const float* __restrict__ features, const int* __restrict__ edges,
    const float* __restrict__ W1, const float* __restrict__ b1,
    const float* __restrict__ W2, const float* __restrict__ b2,
    float* __restrict__ alphas)
{
    __shared__ float m1[4][16];
    const int tid = threadIdx.x;
    const int w = tid >> 6, lane = tid & 63;
    const int e = blockIdx.x * 4 + w;           // grid sized exactly 18000/4
    int i, j;
    if (e < NEDGE) { j = edges[e]; i = edges[NEDGE + e]; }
    else { i = j = e - NEDGE; }

    const int o = lane >> 2, q = lane & 3;      // 16 outputs x 4 partials
    const float* fsrc = (q < 2) ? (features + i * 64 + q * 32)
                                : (features + j * 64 + (q - 2) * 32);
    const float* wsrc = W1 + o * 128 + q * 32;
    float acc = 0.f;
#pragma unroll
    for (int k = 0; k < 32; ++k) acc += fsrc[k] * wsrc[k];
    acc += __shfl_xor(acc, 1);
    acc += __shfl_xor(acc, 2);
    if (q == 0) m1[w][o] = sigm(acc + b1[o]);
    __syncthreads();
    if (lane < 32) {
        const int o2 = lane >> 4, k = lane & 15;
        float p = m1[w][k] * W2[o2 * 16 + k];
        p += __shfl_xor(p, 1);
        p += __shfl_xor(p, 2);
        p += __shfl_xor(p, 4);
        p += __shfl_xor(p, 8);
        if (k == 0) alphas[e * 2 + o2] = sigm(p + b2[o2]);
    }
}

// ---------------------------------------------------------------------------
// MetaGAT (CSR, MFMA, K-split): 2 blocks per dst (M-halves, 48 rows).
// Linearity split: S@w = [a0*(Si@Wa_t)+a1*(Si@Wb_t)+Si@Bc_t] + Sj@w_bot.
// Si-projections (PA/PB/PC) computed ONCE per block via 18 preamble MFMAs,
// held in 36 VGPRs; per edge only w_bot (16 elems/lane) is built and 6 MFMAs
// run on Sj. Double-buffered Sj in LDS -> 1 barrier/edge; register prefetch
// of next edge. Self loop reuses the Si buffer. No atomics.
// ---------------------------------------------------------------------------
__global__ __launch_bounds__(256) void gat_csr_kernel(
    const ushort_t* __restrict__ out1,
    const int* __restrict__ degree, const int* __restrict__ rowstart,
    const int* __restrict__ srcids, const int* __restrict__ eids,
    const float* __restrict__ alphas,
    const float* __restrict__ W3, const float* __restrict__ b3,
    float* __restrict__ agg)
{
    __shared__ ushort_t S[2][48][140] __attribute__((aligned(16)));   // 26880 B

    const int tid = threadIdx.x;
    const int i = blockIdx.x >> 1;
    const int mh = blockIdx.x & 1;        // M-half: local rows map l=(rr>>3)+6*mh
    const int deg = degree[i];
    const int rs = rowstart[i];

    const int wv = tid >> 6;              // N-strip
    const int r = tid & 15;
    const int quad = (tid >> 4) & 3;
    const int n = wv * 16 + r;

    const ushort_t* pi = out1 + i * (NB * LSEQ * HDIM);

    // ---- stage Si half into S[0] (cols 0..63): 768 uint2 chunks ----
#pragma unroll
    for (int p = 0; p < 3; ++p) {
        const int u = p * 256 + tid;
        const int rr = u >> 4, c4 = u & 15;
        const int b = rr & 7, l = (rr >> 3) + 6 * mh;
        *(uint2*)&S[0][rr][c4 * 4] = *(const uint2*)(pi + (b * 12 + l) * 64 + c4 * 4);
    }

    // ---- pin w_bot columns (k = 64 + ks*32 + quad*8 + jj) in registers ----
    float wba[16], wbb[16], wbc[16];
#pragma unroll
    for (int ks = 0; ks < 2; ++ks)
#pragma unroll
        for (int jj = 0; jj < 8; ++jj) {
            const int m = (64 + ks * 32 + quad * 8 + jj) * 64 + n;
            float2 w2 = ((const float2*)W3)[m];
            wba[ks * 8 + jj] = w2.x; wbb[ks * 8 + jj] = w2.y; wbc[ks * 8 + jj] = b3[m];
        }

    // ---- fixed W-top B-frags for the Si-projection preamble ----
    bf16x8 WtA[2], WtB[2], WtC[2];
#pragma unroll
    for (int ks = 0; ks < 2; ++ks) {
        ushort_t ta[8], tb[8], tc[8];
#pragma unroll
        for (int jj = 0; jj < 8; ++jj) {
            const int m = (ks * 32 + quad * 8 + jj) * 64 + n;
            float2 w2 = ((const float2*)W3)[m];
            ta[jj] = fbf(w2.x); tb[jj] = fbf(w2.y); tc[jj] = fbf(b3[m]);
        }
        WtA[ks] = *(bf16x8*)ta; WtB[ks] = *(bf16x8*)tb; WtC[ks] = *(bf16x8*)tc;
    }

    __syncthreads();   // S[0] = Si ready

    // ---- preamble: Si-projections PA/PB/PC (3 M-tiles x f32x4 each) ----
    f32x4 PA[3], PB[3], PC[3];
#pragma unroll
    for (int mt = 0; mt < 3; ++mt) {
        bf16x8 af0 = *(const bf16x8*)&S[0][mt * 16 + r][quad * 8];
        bf16x8 af1 = *(const bf16x8*)&S[0][mt * 16 + r][32 + quad * 8];
        f32x4 pa = {0.f, 0.f, 0.f, 0.f};
        f32x4 pb = {0.f, 0.f, 0.f, 0.f};
        f32x4 pc = {0.f, 0.f, 0.f, 0.f};
        pa = __builtin_amdgcn_mfma_f32_16x16x32_bf16(af0, WtA[0], pa, 0, 0, 0);
        pa = __builtin_amdgcn_mfma_f32_16x16x32_bf16(af1, WtA[1], pa, 0, 0, 0);
        pb = __builtin_amdgcn_mfma_f32_16x16x32_bf16(af0, WtB[0], pb, 0, 0, 0);
        pb = __builtin_amdgcn_mfma_f32_16x16x32_bf16(af1, WtB[1], pb, 0, 0, 0);
        pc = __builtin_amdgcn_mfma_f32_16x16x32_bf16(af0, WtC[0], pc, 0, 0, 0);
        pc = __builtin_amdgcn_mfma_f32_16x16x32_bf16(af1, WtC[1], pc, 0, 0, 0);
        PA[mt] = pa; PB[mt] = pb; PC[mt] = pc;
    }

    float accN[3][4];
#pragma unroll
    for (int mt = 0; mt < 3; ++mt)
#pragma unroll
        for (int g2 = 0; g2 < 4; ++g2) accN[mt][g2] = 0.f;

    // ---- prefetch edge 1's Sj (edge 0 = self loop reuses S[0] = Si) ----
    uint2 pf[3];
    if (deg > 0) {
        const ushort_t* pj = out1 + srcids[rs] * (NB * LSEQ * HDIM);
#pragma unroll
        for (int p = 0; p < 3; ++p) {
            const int u = p * 256 + tid;
            const int rr = u >> 4, c4 = u & 15;
            const int b = rr & 7, l = (rr >> 3) + 6 * mh;
            pf[p] = *(const uint2*)(pj + (b * 12 + l) * 64 + c4 * 4);
        }
    }

    for (int eo = 0; eo <= deg; ++eo) {
        const int buf = eo & 1;
        if (eo >= 1) {
#pragma unroll
            for (int p = 0; p < 3; ++p) {
                const int u = p * 256 + tid;
                const int rr = u >> 4, c4 = u & 15;
                *(uint2*)&S[buf][rr][c4 * 4] = pf[p];
            }
        }
        const int eid = (eo == 0) ? (NEDGE + i) : eids[rs + eo - 1];
        const float2 a01 = *(const float2*)(alphas + eid * 2);
        __syncthreads();   // S[buf] ready (dbuf: eo-2 reads finished pre-barrier(eo-1))

        // prefetch edge eo+1's Sj under this edge's compute
        if (eo < deg) {
            const ushort_t* pj = out1 + srcids[rs + eo] * (NB * LSEQ * HDIM);
#pragma unroll
            for (int p = 0; p < 3; ++p) {
                const int u = p * 256 + tid;
                const int rr = u >> 4, c4 = u & 15;
                const int b = rr & 7, l = (rr >> 3) + 6 * mh;
                pf[p] = *(const uint2*)(pj + (b * 12 + l) * 64 + c4 * 4);
            }
        }

        // per-edge w_bot B-frags (16 elems from pinned registers)
        bf16x8 bfrag[2];
#pragma unroll
        for (int ks = 0; ks < 2; ++ks) {
            ushort_t tmp[8];
#pragma unroll
            for (int jj = 0; jj < 8; ++jj) {
                const int q = ks * 8 + jj;
                tmp[jj] = fbf(fmaf(a01.y, wbb[q], fmaf(a01.x, wba[q], wbc[q])));
            }
            bfrag[ks] = *(bf16x8*)tmp;
        }

#pragma unroll
        for (int mt = 0; mt < 3; ++mt) {
            bf16x8 aj0 = *(const bf16x8*)&S[buf][mt * 16 + r][quad * 8];
            bf16x8 aj1 = *(const bf16x8*)&S[buf][mt * 16 + r][32 + quad * 8];
            f32x4 acc = {0.f, 0.f, 0.f, 0.f};
            acc = __builtin_amdgcn_mfma_f32_16x16x32_bf16(aj0, bfrag[0], acc, 0, 0, 0);
            acc = __builtin_amdgcn_mfma_f32_16x16x32_bf16(aj1, bfrag[1], acc, 0, 0, 0);
            float v[4];
#pragma unroll
            for (int g2 = 0; g2 < 4; ++g2) {
                float x = acc[g2] + fmaf(a01.x, PA[mt][g2],
                              fmaf(a01.y, PB[mt][g2], PC[mt][g2]));
                v[g2] = x > 0.f ? x : 0.01f * x;   // leaky_relu
            }
            float mx = fmaxf(fmaxf(v[0], v[1]), fmaxf(v[2], v[3]));
            mx = fmaxf(mx, __shfl_xor(mx, 16));
            float s = 0.f;
#pragma unroll
            for (int g2 = 0; g2 < 4; ++g2) { v[g2] = __expf(v[g2] - mx); s += v[g2]; }
            s += __shfl_xor(s, 16);
            const float inv = 1.f / s;
#pragma unroll
            for (int g2 = 0; g2 < 4; ++g2) {
                const int lr = mt * 16 + quad * 4 + g2;
                accN[mt][g2] += v[g2] * inv * bf1(S[buf][lr][n]);
            }
        }
    }

    // single non-atomic store of this half-node's aggregate
#pragma unroll
    for (int mt = 0; mt < 3; ++mt)
#pragma unroll
        for (int g2 = 0; g2 < 4; ++g2) {
            const int gr = 48 * mh + mt * 16 + quad * 4 + g2;  // = l*8 + b
            const int b = gr & 7, l = gr >> 3;
            agg[(i * 96 + b * 12 + l) * 64 + n] = accN[mt][g2];
        }
}

// ---------------------------------------------------------------------------
// GRU2: gi AND gh via MFMA; x_t = relu(agg) staged bf16, next-step global
// load software-pipelined under the MFMAs.
// ---------------------------------------------------------------------------
__global__ __launch_bounds__(512, 2) void gru2_kernel(
    const float* __restrict__ agg, const float* __restrict__ Wih,
    const float* __restrict__ Whh, const float* __restrict__ bih,
    const float* __restrict__ bhh, float* __restrict__ h2out)
{
    __shared__ ushort_t H[64][72] __attribute__((aligned(16)));  // 9216 B
    __shared__ ushort_t X[64][72] __attribute__((aligned(16)));  // 9216 B

    const int tid = threadIdx.x;
    const int wv = tid >> 6;
    const int mw = wv & 1, nw = wv >> 1;
    const int c = tid & 15;
    const int quad = (tid >> 4) & 3;
    const int j = nw * 16 + c;
    const int s0 = blockIdx.x * 64;
    const int sl = tid >> 3, k0 = (tid & 7) * 8;

    *(uint4*)&H[tid & 63][(tid >> 6) * 8] = uint4{0, 0, 0, 0};

    bf16x8 Bh[3][2], Bi[3][2];
    float bi[3], bh[3];
#pragma unroll
    for (int g = 0; g < 3; ++g) {
        const int row = g * 64 + j;
        bi[g] = bih[row]; bh[g] = bhh[row];
#pragma unroll
        for (int ks = 0; ks < 2; ++ks) {
            const float* wp = Whh + (row << 6) + ks * 32 + quad * 8;
            float4 wa = *(const float4*)wp;
            float4 wb = *(const float4*)(wp + 4);
            ushort_t tmp[8];
            tmp[0] = fbf(wa.x); tmp[1] = fbf(wa.y); tmp[2] = fbf(wa.z); tmp[3] = fbf(wa.w);
            tmp[4] = fbf(wb.x); tmp[5] = fbf(wb.y); tmp[6] = fbf(wb.z); tmp[7] = fbf(wb.w);
            Bh[g][ks] = *(bf16x8*)tmp;
            const float* wp2 = Wih + (row << 6) + ks * 32 + quad * 8;
            float4 va = *(const float4*)wp2;
            float4 vb = *(const float4*)(wp2 + 4);
            tmp[0] = fbf(va.x); tmp[1] = fbf(va.y); tmp[2] = fbf(va.z); tmp[3] = fbf(va.w);
            tmp[4] = fbf(vb.x); tmp[5] = fbf(vb.y); tmp[6] = fbf(vb.z); tmp[7] = fbf(vb.w);
            Bi[g][ks] = *(bf16x8*)tmp;
        }
    }

    float hold[2][4];
#pragma unroll
    for (int mt = 0; mt < 2; ++mt)
#pragma unroll
        for (int rg = 0; rg < 4; ++rg) hold[mt][rg] = 0.f;

    float xr[8];
    {
        const float* gp = agg + (s0 + sl) * (LSEQ * HDIM) + k0;
        *(float4*)&xr[0] = *(const float4*)gp;
        *(float4*)&xr[4] = *(const float4*)(gp + 4);
    }

    for (int t = 0; t < LSEQ; ++t) {
        {
            ushort_t xs[8];
#pragma unroll
            for (int q = 0; q < 8; ++q) xs[q] = fbf(xr[q] > 0.f ? xr[q] : 0.f);
            *(uint4*)&X[sl][k0] = *(uint4*)xs;
        }
        __syncthreads();   // A: X_t + H_t visible
        if (t < LSEQ - 1) {
            const float* gp = agg + (s0 + sl) * (LSEQ * HDIM) + (t + 1) * HDIM + k0;
            *(float4*)&xr[0] = *(const float4*)gp;
            *(float4*)&xr[4] = *(const float4*)(gp + 4);
        }
#pragma unroll
        for (int mt = 0; mt < 2; ++mt) {
            const int mrow = mw * 32 + mt * 16 + c;
            bf16x8 ah0 = *(const bf16x8*)&H[mrow][quad * 8];
            bf16x8 ah1 = *(const bf16x8*)&H[mrow][32 + quad * 8];
            bf16x8 ax0 = *(const bf16x8*)&X[mrow][quad * 8];
            bf16x8 ax1 = *(const bf16x8*)&X[mrow][32 + quad * 8];
            f32x4 gh[3], gi[3];
#pragma unroll
            for (int g = 0; g < 3; ++g) {
                f32x4 acc = {0.f, 0.f, 0.f, 0.f};
                acc = __builtin_amdgcn_mfma_f32_16x16x32_bf16(ah0, Bh[g][0], acc, 0, 0, 0);
                acc = __builtin_amdgcn_mfma_f32_16x16x32_bf16(ah1, Bh[g][1], acc, 0, 0, 0);
                gh[g] = acc;
                f32x4 acc2 = {0.f, 0.f, 0.f, 0.f};
                acc2 = __builtin_amdgcn_mfma_f32_16x16x32_bf16(ax0, Bi[g][0], acc2, 0, 0, 0);
                acc2 = __builtin_amdgcn_mfma_f32_16x16x32_bf16(ax1, Bi[g][1], acc2, 0, 0, 0);
                gi[g] = acc2;
            }
            ushort_t hnb[4];
#pragma unroll
            for (int rg = 0; rg < 4; ++rg) {
                float r = sigm(bi[0] + gi[0][rg] + bh[0] + gh[0][rg]);
                float z = sigm(bi[1] + gi[1][rg] + bh[1] + gh[1][rg]);
                float n = tanh_fast(bi[2] + gi[2][rg] + r * (bh[2] + gh[2][rg]));
                float hv = (1.f - z) * n + z * hold[mt][rg];
                hold[mt][rg] = hv;
                hnb[rg] = fbf(hv);
            }
            __syncthreads();   // B
#pragma unroll
            for (int rg = 0; rg < 4; ++rg) {
                const int sloc = mw * 32 + mt * 16 + quad * 4 + rg;
                H[sloc][j] = hnb[rg];
            }
        }
    }
#pragma unroll
    for (int mt = 0; mt < 2; ++mt)
#pragma unroll
        for (int rg = 0; rg < 4; ++rg) {
            const int sloc = mw * 32 + mt * 16 + quad * 4 + rg;
            h2out[(s0 + sloc) * HDIM + j] = hold[mt][rg];
        }
}

extern "C" void kernel_launch(void* const* d_in, const int* in_sizes, int n_in,
                              void* d_out, int out_size, void* d_ws, size_t ws_size,
                              hipStream_t stream)
{
    const float* data     = (const float*)d_in[0];
    const float* features = (const float*)d_in[1];
    const int*   edges    = (const int*)d_in[2];
    const float* Wih1     = (const float*)d_in[3];
    const float* Whh1     = (const float*)d_in[4];
    const float* bih1     = (const float*)d_in[5];
    const float* bhh1     = (const float*)d_in[6];
    const float* W1       = (const float*)d_in[7];
    const float* b1       = (const float*)d_in[8];
    const float* W2       = (const float*)d_in[9];
    const float* b2       = (const float*)d_in[10];
    const float* W3       = (const float*)d_in[11];
    const float* b3       = (const float*)d_in[12];
    const float* Wih2     = (const float*)d_in[13];
    const float* Whh2     = (const float*)d_in[14];
    const float* bih2     = (const float*)d_in[15];
    const float* bhh2     = (const float*)d_in[16];

    float*    out  = (float*)d_out;
    char*     ws   = (char*)d_ws;
    ushort_t* out1 = (ushort_t*)ws;                    // bf16 intermediate
    float*    agg  = (float*)(ws + OUT1_BYTES);        // fp32 GAT output
    int*      meta = (int*)(ws + OUT1_BYTES + AGG_BYTES);
    int*   degree   = meta;                       // [2000]
    int*   cursor   = meta + NNODE;               // [2000]
    int*   rowstart = meta + 2 * NNODE;           // [2000]
    int*   srcids   = meta + 3 * NNODE;           // [16000]
    int*   eids     = meta + 3 * NNODE + NEDGE;   // [16000]
    float* alphas   = (float*)(meta + 3 * NNODE + 2 * NEDGE);  // [36000]

    hipMemsetAsync(meta, 0, 2 * NNODE * sizeof(int), stream);   // degree+cursor

    count_kernel<<<(NEDGE + 255) / 256, 256, 0, stream>>>(edges, degree);
    scan_kernel<<<1, 256, 0, stream>>>(degree, rowstart);
    scatter_kernel<<<(NEDGE + 255) / 256, 256, 0, stream>>>(edges, rowstart, cursor,
                                                            srcids, eids);
    alpha_kernel<<<(NEDGE + NNODE) / 4, 256, 0, stream>>>(features, edges,
                                                          W1, b1, W2, b2, alphas);

    gru1_kernel<<<NSEQ / 64, 512, 0, stream>>>(data, Wih1, Whh1, bih1, bhh1, out1, out);
    gat_csr_kernel<<<2 * NNODE, 256, 0, stream>>>(out1, degree, rowstart, srcids, eids,
                                                  alphas, W3, b3, agg);
    gru2_kernel<<<NSEQ / 64, 512, 0, stream>>>(agg, Wih2, Whh2, bih2, bhh2,
                                               out + NNODE * NB * HDIM);
}

// Round 9
// 341.518 us; speedup vs baseline: 7.4231x; 1.0319x over previous
//
#include <hip/hip_runtime.h>
#include <hip/hip_bf16.h>

typedef unsigned short ushort_t;
typedef unsigned int uint_t;
typedef __attribute__((ext_vector_type(8))) short bf16x8;
typedef __attribute__((ext_vector_type(4))) float f32x4;

#define NNODE 2000
#define NB 8
#define LSEQ 12
#define HDIM 64
#define NEDGE 16000
#define NSEQ (NNODE * NB)            // 16000 sequences
#define OUT1_ELEMS (NNODE * NB * LSEQ * HDIM)   // 12,288,000
#define OUT1_BYTES (OUT1_ELEMS * 2)             // bf16 intermediate: 24,576,000
#define AGG_BYTES  (OUT1_ELEMS * 4)             // fp32: 49,152,000

__device__ __forceinline__ float bf1(ushort_t u) { return __uint_as_float(((uint_t)u) << 16); }
__device__ __forceinline__ ushort_t fbf(float f) {
    uint_t x = __float_as_uint(f);
    uint_t r = x + 0x7fffu + ((x >> 16) & 1u);   // RNE
    return (ushort_t)(r >> 16);
}
__device__ __forceinline__ uint_t pk2(float lo, float hi) {
    __hip_bfloat162 t = __float22bfloat162_rn(float2{lo, hi});
    return *(uint_t*)&t;   // low ushort = bf(lo)
}
__device__ __forceinline__ float sigm(float x) { return 1.f / (1.f + __expf(-x)); }
__device__ __forceinline__ float tanh_fast(float x) { return 2.f / (1.f + __expf(-2.f * x)) - 1.f; }

// ===========================================================================
// MFMA geometry (HW-verified R3): A[m=lane&15][k=quad*8+jj];
// B[k=ks*32+quad*8+jj][n=lane&15]; C row(M)=quad*4+reg, col(N)=lane&15.
// ===========================================================================

// ---------------------------------------------------------------------------
// GRU1: x_t is only 2-wide -> gi on VALU; gh via MFMA. out1 bf16 per step.
// ---------------------------------------------------------------------------
__global__ __launch_bounds__(512, 2) void gru1_kernel(
    const float* __restrict__ data, const float* __restrict__ Wih,
    const float* __restrict__ Whh, const float* __restrict__ bih,
    const float* __restrict__ bhh, ushort_t* __restrict__ out1,
    float* __restrict__ h1out)
{
    __shared__ ushort_t H[64][72] __attribute__((aligned(16)));  // 9216 B
    __shared__ float XD[64][26];                                 // 6656 B

    const int tid = threadIdx.x;
    const int wv = tid >> 6;
    const int mw = wv & 1, nw = wv >> 1;
    const int c = tid & 15;
    const int quad = (tid >> 4) & 3;
    const int j = nw * 16 + c;
    const int s0 = blockIdx.x * 64;

    *(uint4*)&H[tid & 63][(tid >> 6) * 8] = uint4{0, 0, 0, 0};
#pragma unroll
    for (int p = 0; p < 3; ++p) {
        const int flat = p * 512 + tid;     // 0..1535
        const int sl = flat / 24, q = flat - sl * 24;
        XD[sl][q] = data[(s0 + sl) * 24 + q];
    }

    bf16x8 Bh[3][2];
    float wi0[3], wi1[3], bi[3], bh[3];
#pragma unroll
    for (int g = 0; g < 3; ++g) {
        const int row = g * 64 + j;
        float2 wi = *(const float2*)(Wih + row * 2);
        wi0[g] = wi.x; wi1[g] = wi.y;
        bi[g] = bih[row]; bh[g] = bhh[row];
#pragma unroll
        for (int ks = 0; ks < 2; ++ks) {
            const float* wp = Whh + (row << 6) + ks * 32 + quad * 8;
            float4 wa = *(const float4*)wp;
            float4 wb = *(const float4*)(wp + 4);
            ushort_t tmp[8];
            tmp[0] = fbf(wa.x); tmp[1] = fbf(wa.y); tmp[2] = fbf(wa.z); tmp[3] = fbf(wa.w);
            tmp[4] = fbf(wb.x); tmp[5] = fbf(wb.y); tmp[6] = fbf(wb.z); tmp[7] = fbf(wb.w);
            Bh[g][ks] = *(bf16x8*)tmp;
        }
    }

    float hold[2][4];
#pragma unroll
    for (int mt = 0; mt < 2; ++mt)
#pragma unroll
        for (int rg = 0; rg < 4; ++rg) hold[mt][rg] = 0.f;

    for (int t = 0; t < LSEQ; ++t) {
        __syncthreads();   // A: H (+XD at t=0) visible
#pragma unroll
        for (int mt = 0; mt < 2; ++mt) {
            bf16x8 a0 = *(const bf16x8*)&H[mw * 32 + mt * 16 + c][quad * 8];
            bf16x8 a1 = *(const bf16x8*)&H[mw * 32 + mt * 16 + c][32 + quad * 8];
            f32x4 gh[3];
#pragma unroll
            for (int g = 0; g < 3; ++g) {
                f32x4 acc = {0.f, 0.f, 0.f, 0.f};
                acc = __builtin_amdgcn_mfma_f32_16x16x32_bf16(a0, Bh[g][0], acc, 0, 0, 0);
                acc = __builtin_amdgcn_mfma_f32_16x16x32_bf16(a1, Bh[g][1], acc, 0, 0, 0);
                gh[g] = acc;
            }
            ushort_t hnb[4];
#pragma unroll
            for (int rg = 0; rg < 4; ++rg) {
                const int sloc = mw * 32 + mt * 16 + quad * 4 + rg;
                float2 xp = *(const float2*)&XD[sloc][2 * t];
                float gr = bh[0] + gh[0][rg];
                float gz = bh[1] + gh[1][rg];
                float gn = bh[2] + gh[2][rg];
                float ir = bi[0] + wi0[0] * xp.x + wi1[0] * xp.y;
                float iz = bi[1] + wi0[1] * xp.x + wi1[1] * xp.y;
                float in = bi[2] + wi0[2] * xp.x + wi1[2] * xp.y;
                float r = sigm(ir + gr);
                float z = sigm(iz + gz);
                float n = tanh_fast(in + r * gn);
                float hv = (1.f - z) * n + z * hold[mt][rg];
                hold[mt][rg] = hv;
                hnb[rg] = fbf(hv);
            }
            __syncthreads();   // B
#pragma unroll
            for (int rg = 0; rg < 4; ++rg) {
                const int sloc = mw * 32 + mt * 16 + quad * 4 + rg;
                H[sloc][j] = hnb[rg];
                out1[(s0 + sloc) * (LSEQ * HDIM) + t * HDIM + j] = hnb[rg];
            }
        }
    }
#pragma unroll
    for (int mt = 0; mt < 2; ++mt)
#pragma unroll
        for (int rg = 0; rg < 4; ++rg) {
            const int sloc = mw * 32 + mt * 16 + quad * 4 + rg;
            h1out[(s0 + sloc) * HDIM + j] = hold[mt][rg];
        }
}

// ---------------------------------------------------------------------------
// CSR helpers: degree histogram -> single-block scan -> scatter src+edge ids.
// ---------------------------------------------------------------------------
__global__ __launch_bounds__(256) void count_kernel(const int* __restrict__ edges,
                                                    int* __restrict__ degree)
{
    const int e = blockIdx.x * 256 + threadIdx.x;
    if (e < NEDGE) atomicAdd(&degree[edges[NEDGE + e]], 1);
}

__global__ __launch_bounds__(256) void scan_kernel(const int* __restrict__ degree,
                                                   int* __restrict__ rowstart)
{
    __shared__ int part[256];
    const int t = threadIdx.x;
    const int base = t * 8;
    int s = 0;
#pragma unroll
    for (int q = 0; q < 8; ++q) { const int idx = base + q; if (idx < NNODE) s += degree[idx]; }
    part[t] = s;
    __syncthreads();
    if (t == 0) {
        int run = 0;
        for (int u = 0; u < 256; ++u) { const int v = part[u]; part[u] = run; run += v; }
    }
    __syncthreads();
    int run = part[t];
#pragma unroll
    for (int q = 0; q < 8; ++q) {
        const int idx = base + q;
        if (idx < NNODE) { rowstart[idx] = run; run += degree[idx]; }
    }
}

__global__ __launch_bounds__(256) void scatter_kernel(const int* __restrict__ edges,
                                                      const int* __restrict__ rowstart,
                                                      int* __restrict__ cursor,
                                                      int* __restrict__ srcids,
                                                      int* __restrict__ eids)
{
    const int e = blockIdx.x * 256 + threadIdx.x;
    if (e < NEDGE) {
        const int d = edges[NEDGE + e];
        const int pos = atomicAdd(&cursor[d], 1);
        srcids[rowstart[d] + pos] = edges[e];   // src node
        eids[rowstart[d] + pos] = e;            // edge id (alpha index)
    }
}

// ---------------------------------------------------------------------------
// Per-edge MLP hoisted: alphas[2e] = (a0,a1), all 18000 edges incl. self.
// ---------------------------------------------------------------------------
__global__ __launch_bounds__(256) void alpha_kernel(
    const float* __restrict__ features, const int* __restrict__ edges,
    const float* __restrict__ W1, const float* __restrict__ b1,
    const float* __restrict__ W2, const float* __restrict__ b2,
    float* __restrict__ alphas)
{
    __shared__ float m1[4][16];
    const int tid = threadIdx.x;
    const int w = tid >> 6, lane = tid & 63;
    const int e = blockIdx.x * 4 + w;           // grid sized exactly 18000/4
    int i, j;
    if (e < NEDGE) { j = edges[e]; i = edges[NEDGE + e]; }
    else { i = j = e - NEDGE; }

    const int o = lane >> 2, q = lane & 3;      // 16 outputs x 4 partials
    const float* fsrc = (q < 2) ? (features + i * 64 + q * 32)
                                : (features + j * 64 + (q - 2) * 32);
    const float* wsrc = W1 + o * 128 + q * 32;
    float acc = 0.f;
#pragma unroll
    for (int k = 0; k < 32; ++k) acc += fsrc[k] * wsrc[k];
    acc += __shfl_xor(acc, 1);
    acc += __shfl_xor(acc, 2);
    if (q == 0) m1[w][o] = sigm(acc + b1[o]);
    __syncthreads();
    if (lane < 32) {
        const int o2 = lane >> 4, k = lane & 15;
        float p = m1[w][k] * W2[o2 * 16 + k];
        p += __shfl_xor(p, 1);
        p += __shfl_xor(p, 2);
        p += __shfl_xor(p, 4);
        p += __shfl_xor(p, 8);
        if (k == 0) alphas[e * 2 + o2] = sigm(p + b2[o2]);
    }
}

// ---------------------------------------------------------------------------
// MetaGAT (CSR, MFMA, K-split, PAIR-BATCHED): 2 blocks per dst (M-halves).
// S@w = [a0*(Si@Wa_t)+a1*(Si@Wb_t)+Si@Bc_t] + Sj@w_bot; Si-projections once
// per block (18 preamble MFMAs, 36 VGPRs). Edge loop processes TWO edges per
// barrier: 4 rotating Sj slots (pair-granularity dbuf) + register prefetch,
// so two edges' compute covers the pair's global-load latency. Row stride 72
// (36 dw): optimal-8 bank spread for b128. No atomics.
// ---------------------------------------------------------------------------
__global__ __launch_bounds__(256) void gat_csr_kernel(
    const ushort_t* __restrict__ out1,
    const int* __restrict__ degree, const int* __restrict__ rowstart,
    const int* __restrict__ srcids, const int* __restrict__ eids,
    const float* __restrict__ alphas,
    const float* __restrict__ W3, const float* __restrict__ b3,
    float* __restrict__ agg)
{
    __shared__ ushort_t Si[48][72] __attribute__((aligned(16)));     // 6912 B
    __shared__ ushort_t SS[4][48][72] __attribute__((aligned(16)));  // 27648 B

    const int tid = threadIdx.x;
    const int i = blockIdx.x >> 1;
    const int mh = blockIdx.x & 1;        // M-half: local rows map l=(rr>>3)+6*mh
    const int deg = degree[i];
    const int rs = rowstart[i];

    const int wv = tid >> 6;              // N-strip
    const int r = tid & 15;
    const int quad = (tid >> 4) & 3;
    const int n = wv * 16 + r;

    // staging lane mapping (768 uint2 per 48x64 tile)
    const int srr = tid >> 4, sc4 = tid & 15;        // row, col-group base
    const int sb = srr & 7, sl_ = (srr >> 3) + 6 * mh;
    const int goff = (sb * 12 + sl_) * 64 + sc4 * 4; // global elem offset in node

    const ushort_t* pi = out1 + i * (NB * LSEQ * HDIM);

    // ---- stage Si (cols 0..63) ----
#pragma unroll
    for (int p = 0; p < 3; ++p) {
        const int u = p * 256 + tid;
        const int rr = u >> 4, c4 = u & 15;
        const int b = rr & 7, l = (rr >> 3) + 6 * mh;
        *(uint2*)&Si[rr][c4 * 4] = *(const uint2*)(pi + (b * 12 + l) * 64 + c4 * 4);
    }

    // ---- pin w_bot columns (k = 64 + ks*32 + quad*8 + jj) in registers ----
    float wba[16], wbb[16], wbc[16];
#pragma unroll
    for (int ks = 0; ks < 2; ++ks)
#pragma unroll
        for (int jj = 0; jj < 8; ++jj) {
            const int m = (64 + ks * 32 + quad * 8 + jj) * 64 + n;
            float2 w2 = ((const float2*)W3)[m];
            wba[ks * 8 + jj] = w2.x; wbb[ks * 8 + jj] = w2.y; wbc[ks * 8 + jj] = b3[m];
        }

    // ---- fixed W-top B-frags for the Si-projection preamble ----
    bf16x8 WtA[2], WtB[2], WtC[2];
#pragma unroll
    for (int ks = 0; ks < 2; ++ks) {
        ushort_t ta[8], tb[8], tc[8];
#pragma unroll
        for (int jj = 0; jj < 8; ++jj) {
            const int m = (ks * 32 + quad * 8 + jj) * 64 + n;
            float2 w2 = ((const float2*)W3)[m];
            ta[jj] = fbf(w2.x); tb[jj] = fbf(w2.y); tc[jj] = fbf(b3[m]);
        }
        WtA[ks] = *(bf16x8*)ta; WtB[ks] = *(bf16x8*)tb; WtC[ks] = *(bf16x8*)tc;
    }

    __syncthreads();   // Si ready

    // ---- preamble: Si-projections PA/PB/PC ----
    f32x4 PA[3], PB[3], PC[3];
#pragma unroll
    for (int mt = 0; mt < 3; ++mt) {
        bf16x8 af0 = *(const bf16x8*)&Si[mt * 16 + r][quad * 8];
        bf16x8 af1 = *(const bf16x8*)&Si[mt * 16 + r][32 + quad * 8];
        f32x4 pa = {0.f, 0.f, 0.f, 0.f};
        f32x4 pb = {0.f, 0.f, 0.f, 0.f};
        f32x4 pc = {0.f, 0.f, 0.f, 0.f};
        pa = __builtin_amdgcn_mfma_f32_16x16x32_bf16(af0, WtA[0], pa, 0, 0, 0);
        pa = __builtin_amdgcn_mfma_f32_16x16x32_bf16(af1, WtA[1], pa, 0, 0, 0);
        pb = __builtin_amdgcn_mfma_f32_16x16x32_bf16(af0, WtB[0], pb, 0, 0, 0);
        pb = __builtin_amdgcn_mfma_f32_16x16x32_bf16(af1, WtB[1], pb, 0, 0, 0);
        pc = __builtin_amdgcn_mfma_f32_16x16x32_bf16(af0, WtC[0], pc, 0, 0, 0);
        pc = __builtin_amdgcn_mfma_f32_16x16x32_bf16(af1, WtC[1], pc, 0, 0, 0);
        PA[mt] = pa; PB[mt] = pb; PC[mt] = pc;
    }

    float accN[3][4];
#pragma unroll
    for (int mt = 0; mt < 3; ++mt)
#pragma unroll
        for (int g2 = 0; g2 < 4; ++g2) accN[mt][g2] = 0.f;

    // process one edge from an LDS tile (K-split einsum + softmax + msg)
    auto process = [&](const ushort_t (*SB)[72], float2 a01) {
        bf16x8 bfrag[2];
#pragma unroll
        for (int ks = 0; ks < 2; ++ks) {
            uint_t tmp[4];
#pragma unroll
            for (int q2 = 0; q2 < 4; ++q2) {
                const int q = ks * 8 + q2 * 2;
                float f0 = fmaf(a01.y, wbb[q], fmaf(a01.x, wba[q], wbc[q]));
                float f1 = fmaf(a01.y, wbb[q + 1], fmaf(a01.x, wba[q + 1], wbc[q + 1]));
                tmp[q2] = pk2(f0, f1);
            }
            bfrag[ks] = *(bf16x8*)tmp;
        }
#pragma unroll
        for (int mt = 0; mt < 3; ++mt) {
            bf16x8 aj0 = *(const bf16x8*)&SB[mt * 16 + r][quad * 8];
            bf16x8 aj1 = *(const bf16x8*)&SB[mt * 16 + r][32 + quad * 8];
            f32x4 acc = {0.f, 0.f, 0.f, 0.f};
            acc = __builtin_amdgcn_mfma_f32_16x16x32_bf16(aj0, bfrag[0], acc, 0, 0, 0);
            acc = __builtin_amdgcn_mfma_f32_16x16x32_bf16(aj1, bfrag[1], acc, 0, 0, 0);
            float v[4];
#pragma unroll
            for (int g2 = 0; g2 < 4; ++g2) {
                float x = acc[g2] + fmaf(a01.x, PA[mt][g2],
                              fmaf(a01.y, PB[mt][g2], PC[mt][g2]));
                v[g2] = x > 0.f ? x : 0.01f * x;   // leaky_relu
            }
            float mx = fmaxf(fmaxf(v[0], v[1]), fmaxf(v[2], v[3]));
            mx = fmaxf(mx, __shfl_xor(mx, 16));
            float s = 0.f;
#pragma unroll
            for (int g2 = 0; g2 < 4; ++g2) { v[g2] = __expf(v[g2] - mx); s += v[g2]; }
            s += __shfl_xor(s, 16);
            const float inv = 1.f / s;
#pragma unroll
            for (int g2 = 0; g2 < 4; ++g2) {
                const int lr = mt * 16 + quad * 4 + g2;
                accN[mt][g2] += v[g2] * inv * bf1(SB[lr][n]);
            }
        }
    };

    // ---- prefetch CSR edges 0,1 into registers ----
    uint2 pfA[3], pfB[3];
    {
        const ushort_t* pA = out1 + ((deg >= 1) ? srcids[rs] : 0) * (NB * LSEQ * HDIM);
        const ushort_t* pB = out1 + ((deg >= 2) ? srcids[rs + 1] : 0) * (NB * LSEQ * HDIM);
#pragma unroll
        for (int p = 0; p < 3; ++p) {
            pfA[p] = *(const uint2*)(pA + goff + (p * 256 >> 4) * 0 + ((p * 256 + tid) >> 4 != srr ? 0 : 0));
            (void)0;
        }
        // (recompute mapping per p explicitly)
#pragma unroll
        for (int p = 0; p < 3; ++p) {
            const int u = p * 256 + tid;
            const int rr = u >> 4, c4 = u & 15;
            const int b = rr & 7, l = (rr >> 3) + 6 * mh;
            pfA[p] = *(const uint2*)(pA + (b * 12 + l) * 64 + c4 * 4);
            pfB[p] = *(const uint2*)(pB + (b * 12 + l) * 64 + c4 * 4);
        }
    }

    // ---- self loop (uses Si tile directly) ----
    process((const ushort_t (*)[72])Si, *(const float2*)(alphas + (NEDGE + i) * 2));

    const int npairs = (deg + 1) >> 1;
    for (int pk = 0; pk < npairs; ++pk) {
        ushort_t (*SA)[72] = SS[2 * (pk & 1)];
        ushort_t (*SB)[72] = SS[2 * (pk & 1) + 1];
#pragma unroll
        for (int p = 0; p < 3; ++p) {
            const int u = p * 256 + tid;
            const int rr = u >> 4, c4 = u & 15;
            *(uint2*)&SA[rr][c4 * 4] = pfA[p];
            *(uint2*)&SB[rr][c4 * 4] = pfB[p];
        }
        const int base = pk * 2;
        const float2 aA = *(const float2*)(alphas + eids[rs + base] * 2);
        const bool hasB = (base + 1) < deg;
        float2 aB = float2{0.f, 0.f};
        if (hasB) aB = *(const float2*)(alphas + eids[rs + base + 1] * 2);
        __syncthreads();   // pair tiles ready (slots from pair pk-1 fully read pre-barrier)

        // prefetch next pair under this pair's compute
        if (base + 2 < deg) {
            const ushort_t* pA = out1 + srcids[rs + base + 2] * (NB * LSEQ * HDIM);
#pragma unroll
            for (int p = 0; p < 3; ++p) {
                const int u = p * 256 + tid;
                const int rr = u >> 4, c4 = u & 15;
                const int b = rr & 7, l = (rr >> 3) + 6 * mh;
                pfA[p] = *(const uint2*)(pA + (b * 12 + l) * 64 + c4 * 4);
            }
        }
        if (base + 3 < deg) {
            const ushort_t* pB = out1 + srcids[rs + base + 3] * (NB * LSEQ * HDIM);
#pragma unroll
            for (int p = 0; p < 3; ++p) {
                const int u = p * 256 + tid;
                const int rr = u >> 4, c4 = u & 15;
                const int b = rr & 7, l = (rr >> 3) + 6 * mh;
                pfB[p] = *(const uint2*)(pB + (b * 12 + l) * 64 + c4 * 4);
            }
        }

        process((const ushort_t (*)[72])SA, aA);
        if (hasB) process((const ushort_t (*)[72])SB, aB);
    }

    // single non-atomic store of this half-node's aggregate
#pragma unroll
    for (int mt = 0; mt < 3; ++mt)
#pragma unroll
        for (int g2 = 0; g2 < 4; ++g2) {
            const int gr = 48 * mh + mt * 16 + quad * 4 + g2;  // = l*8 + b
            const int b = gr & 7, l = gr >> 3;
            agg[(i * 96 + b * 12 + l) * 64 + n] = accN[mt][g2];
        }
}

// ---------------------------------------------------------------------------
// GRU2: gi AND gh via MFMA; x_t = relu(agg) staged bf16, next-step global
// load software-pipelined under the MFMAs.
// ---------------------------------------------------------------------------
__global__ __launch_bounds__(512, 2) void gru2_kernel(
    const float* __restrict__ agg, const float* __restrict__ Wih,
    const float* __restrict__ Whh, const float* __restrict__ bih,
    const float* __restrict__ bhh, float* __restrict__ h2out)
{
    __shared__ ushort_t H[64][72] __attribute__((aligned(16)));  // 9216 B
    __shared__ ushort_t X[64][72] __attribute__((aligned(16)));  // 9216 B

    const int tid = threadIdx.x;
    const int wv = tid >> 6;
    const int mw = wv & 1, nw = wv >> 1;
    const int c = tid & 15;
    const int quad = (tid >> 4) & 3;
    const int j = nw * 16 + c;
    const int s0 = blockIdx.x * 64;
    const int sl = tid >> 3, k0 = (tid & 7) * 8;

    *(uint4*)&H[tid & 63][(tid >> 6) * 8] = uint4{0, 0, 0, 0};

    bf16x8 Bh[3][2], Bi[3][2];
    float bi[3], bh[3];
#pragma unroll
    for (int g = 0; g < 3; ++g) {
        const int row = g * 64 + j;
        bi[g] = bih[row]; bh[g] = bhh[row];
#pragma unroll
        for (int ks = 0; ks < 2; ++ks) {
            const float* wp = Whh + (row << 6) + ks * 32 + quad * 8;
            float4 wa = *(const float4*)wp;
            float4 wb = *(const float4*)(wp + 4);
            ushort_t tmp[8];
            tmp[0] = fbf(wa.x); tmp[1] = fbf(wa.y); tmp[2] = fbf(wa.z); tmp[3] = fbf(wa.w);
            tmp[4] = fbf(wb.x); tmp[5] = fbf(wb.y); tmp[6] = fbf(wb.z); tmp[7] = fbf(wb.w);
            Bh[g][ks] = *(bf16x8*)tmp;
            const float* wp2 = Wih + (row << 6) + ks * 32 + quad * 8;
            float4 va = *(const float4*)wp2;
            float4 vb = *(const float4*)(wp2 + 4);
            tmp[0] = fbf(va.x); tmp[1] = fbf(va.y); tmp[2] = fbf(va.z); tmp[3] = fbf(va.w);
            tmp[4] = fbf(vb.x); tmp[5] = fbf(vb.y); tmp[6] = fbf(vb.z); tmp[7] = fbf(vb.w);
            Bi[g][ks] = *(bf16x8*)tmp;
        }
    }

    float hold[2][4];
#pragma unroll
    for (int mt = 0; mt < 2; ++mt)
#pragma unroll
        for (int rg = 0; rg < 4; ++rg) hold[mt][rg] = 0.f;

    float xr[8];
    {
        const float* gp = agg + (s0 + sl) * (LSEQ * HDIM) + k0;
        *(float4*)&xr[0] = *(const float4*)gp;
        *(float4*)&xr[4] = *(const float4*)(gp + 4);
    }

    for (int t = 0; t < LSEQ; ++t) {
        {
            ushort_t xs[8];
#pragma unroll
            for (int q = 0; q < 8; ++q) xs[q] = fbf(xr[q] > 0.f ? xr[q] : 0.f);
            *(uint4*)&X[sl][k0] = *(uint4*)xs;
        }
        __syncthreads();   // A: X_t + H_t visible
        if (t < LSEQ - 1) {
            const float* gp = agg + (s0 + sl) * (LSEQ * HDIM) + (t + 1) * HDIM + k0;
            *(float4*)&xr[0] = *(const float4*)gp;
            *(float4*)&xr[4] = *(const float4*)(gp + 4);
        }
#pragma unroll
        for (int mt = 0; mt < 2; ++mt) {
            const int mrow = mw * 32 + mt * 16 + c;
            bf16x8 ah0 = *(const bf16x8*)&H[mrow][quad * 8];
            bf16x8 ah1 = *(const bf16x8*)&H[mrow][32 + quad * 8];
            bf16x8 ax0 = *(const bf16x8*)&X[mrow][quad * 8];
            bf16x8 ax1 = *(const bf16x8*)&X[mrow][32 + quad * 8];
            f32x4 gh[3], gi[3];
#pragma unroll
            for (int g = 0; g < 3; ++g) {
                f32x4 acc = {0.f, 0.f, 0.f, 0.f};
                acc = __builtin_amdgcn_mfma_f32_16x16x32_bf16(ah0, Bh[g][0], acc, 0, 0, 0);
                acc = __builtin_amdgcn_mfma_f32_16x16x32_bf16(ah1, Bh[g][1], acc, 0, 0, 0);
                gh[g] = acc;
                f32x4 acc2 = {0.f, 0.f, 0.f, 0.f};
                acc2 = __builtin_amdgcn_mfma_f32_16x16x32_bf16(ax0, Bi[g][0], acc2, 0, 0, 0);
                acc2 = __builtin_amdgcn_mfma_f32_16x16x32_bf16(ax1, Bi[g][1], acc2, 0, 0, 0);
                gi[g] = acc2;
            }
            ushort_t hnb[4];
#pragma unroll
            for (int rg = 0; rg < 4; ++rg) {
                float r = sigm(bi[0] + gi[0][rg] + bh[0] + gh[0][rg]);
                float z = sigm(bi[1] + gi[1][rg] + bh[1] + gh[1][rg]);
                float n = tanh_fast(bi[2] + gi[2][rg] + r * (bh[2] + gh[2][rg]));
                float hv = (1.f - z) * n + z * hold[mt][rg];
                hold[mt][rg] = hv;
                hnb[rg] = fbf(hv);
            }
            __syncthreads();   // B
#pragma unroll
            for (int rg = 0; rg < 4; ++rg) {
                const int sloc = mw * 32 + mt * 16 + quad * 4 + rg;
                H[sloc][j] = hnb[rg];
            }
        }
    }
#pragma unroll
    for (int mt = 0; mt < 2; ++mt)
#pragma unroll
        for (int rg = 0; rg < 4; ++rg) {
            const int sloc = mw * 32 + mt * 16 + quad * 4 + rg;
            h2out[(s0 + sloc) * HDIM + j] = hold[mt][rg];
        }
}

extern "C" void kernel_launch(void* const* d_in, const int* in_sizes, int n_in,
                              void* d_out, int out_size, void* d_ws, size_t ws_size,
                              hipStream_t stream)
{
    const float* data     = (const float*)d_in[0];
    const float* features = (const float*)d_in[1];
    const int*   edges    = (const int*)d_in[2];
    const float* Wih1     = (const float*)d_in[3];
    const float* Whh1     = (const float*)d_in[4];
    const float* bih1     = (const float*)d_in[5];
    const float* bhh1     = (const float*)d_in[6];
    const float* W1       = (const float*)d_in[7];
    const float* b1       = (const float*)d_in[8];
    const float* W2       = (const float*)d_in[9];
    const float* b2       = (const float*)d_in[10];
    const float* W3       = (const float*)d_in[11];
    const float* b3       = (const float*)d_in[12];
    const float* Wih2     = (const float*)d_in[13];
    const float* Whh2     = (const float*)d_in[14];
    const float* bih2     = (const float*)d_in[15];
    const float* bhh2     = (const float*)d_in[16];

    float*    out  = (float*)d_out;
    char*     ws   = (char*)d_ws;
    ushort_t* out1 = (ushort_t*)ws;                    // bf16 intermediate
    float*    agg  = (float*)(ws + OUT1_BYTES);        // fp32 GAT output
    int*      meta = (int*)(ws + OUT1_BYTES + AGG_BYTES);
    int*   degree   = meta;                       // [2000]
    int*   cursor   = meta + NNODE;               // [2000]
    int*   rowstart = meta + 2 * NNODE;           // [2000]
    int*   srcids   = meta + 3 * NNODE;           // [16000]
    int*   eids     = meta + 3 * NNODE + NEDGE;   // [16000]
    float* alphas   = (float*)(meta + 3 * NNODE + 2 * NEDGE);  // [36000]

    hipMemsetAsync(meta, 0, 2 * NNODE * sizeof(int), stream);   // degree+cursor

    count_kernel<<<(NEDGE + 255) / 256, 256, 0, stream>>>(edges, degree);
    scan_kernel<<<1, 256, 0, stream>>>(degree, rowstart);
    scatter_kernel<<<(NEDGE + 255) / 256, 256, 0, stream>>>(edges, rowstart, cursor,
                                                            srcids, eids);
    alpha_kernel<<<(NEDGE + NNODE) / 4, 256, 0, stream>>>(features, edges,
                                                          W1, b1, W2, b2, alphas);

    gru1_kernel<<<NSEQ / 64, 512, 0, stream>>>(data, Wih1, Whh1, bih1, bhh1, out1, out);
    gat_csr_kernel<<<2 * NNODE, 256, 0, stream>>>(out1, degree, rowstart, srcids, eids,
                                                  alphas, W3, b3, agg);
    gru2_kernel<<<NSEQ / 64, 512, 0, stream>>>(agg, Wih2, Whh2, bih2, bhh2,
                                               out + NNODE * NB * HDIM);
}